// Round 2
// baseline (1347.235 us; speedup 1.0000x reference)
//
#include <hip/hip_runtime.h>
#include <cstdint>
#include <cstddef>

typedef __bf16 bf16;
typedef __bf16 bf16x8 __attribute__((ext_vector_type(8)));
typedef float floatx4 __attribute__((ext_vector_type(4)));

#define GLD16(gp, lp) __builtin_amdgcn_global_load_lds( \
    (const __attribute__((address_space(1))) void*)(gp), \
    (__attribute__((address_space(3))) void*)(lp), 16, 0, 0)

// ---------------------------------------------------------------------------
// NT GEMM (augment): C[M,N] += A[M,K] * B[N,K]^T, bf16 in, fp32 atomic accum.
// Exact for integer-valued inputs (products & sums < 2^24).
// ---------------------------------------------------------------------------
__global__ __launch_bounds__(256) void gemm_nt_acc(
    const bf16* __restrict__ A, const bf16* __restrict__ B, float* __restrict__ C,
    int lda, int ldb, int ldc, int kIters)
{
  __shared__ __align__(16) bf16 smem[2 * 128 * 32];
  bf16* As = smem;
  bf16* Bs = smem + 128 * 32;

  const int t = threadIdx.x;
  const int w = t >> 6;
  const int l = t & 63;
  const int wr = w >> 1, wc = w & 1;
  const int lr = l & 15, q = l >> 4;

  const int m0 = blockIdx.x * 128;
  const int n0 = blockIdx.y * 128;
  const int k0base = blockIdx.z * kIters * 32;

  const bf16* Ab = A + (size_t)m0 * lda + k0base;
  const bf16* Bb = B + (size_t)n0 * ldb + k0base;

  const int srow = t >> 2;
  const int schunk = (t & 3) * 8;

  floatx4 acc[4][4];
#pragma unroll
  for (int i = 0; i < 4; ++i)
#pragma unroll
    for (int j = 0; j < 4; ++j) acc[i][j] = (floatx4)0.0f;

  for (int kb = 0; kb < kIters; ++kb) {
    const int k0 = kb * 32;
    __syncthreads();
    GLD16(Ab + (size_t)srow * lda + k0 + schunk,        As + (size_t)t * 8);
    GLD16(Ab + (size_t)(srow + 64) * lda + k0 + schunk, As + (size_t)(t + 256) * 8);
    GLD16(Bb + (size_t)srow * ldb + k0 + schunk,        Bs + (size_t)t * 8);
    GLD16(Bb + (size_t)(srow + 64) * ldb + k0 + schunk, Bs + (size_t)(t + 256) * 8);
    __syncthreads();

    bf16x8 af[4], bfr[4];
#pragma unroll
    for (int mi = 0; mi < 4; ++mi)
      af[mi] = *(const bf16x8*)&As[(wr * 64 + mi * 16 + lr) * 32 + q * 8];
#pragma unroll
    for (int ni = 0; ni < 4; ++ni)
      bfr[ni] = *(const bf16x8*)&Bs[(wc * 64 + ni * 16 + lr) * 32 + q * 8];
#pragma unroll
    for (int mi = 0; mi < 4; ++mi)
#pragma unroll
      for (int ni = 0; ni < 4; ++ni)
        acc[mi][ni] = __builtin_amdgcn_mfma_f32_16x16x32_bf16(
            af[mi], bfr[ni], acc[mi][ni], 0, 0, 0);
  }

#pragma unroll
  for (int mi = 0; mi < 4; ++mi) {
#pragma unroll
    for (int ni = 0; ni < 4; ++ni) {
      const int col = n0 + wc * 64 + ni * 16 + lr;
      const int rowb = m0 + wr * 64 + mi * 16 + q * 4;
#pragma unroll
      for (int r = 0; r < 4; ++r)
        atomicAdd(&C[(size_t)(rowb + r) * ldc + col], acc[mi][ni][r]);
    }
  }
}

// ---------------------------------------------------------------------------
// Z[nr,128] = dn ⊙ (X @ W), fp32-accurate via 3-way bf16 split, 6-term MFMA.
// W pre-split transposed: Wh/Wm/Wl layout [c][k] (128x128 per layer).
// One block = 128 rows. Error ~2^-24 relative.
// ---------------------------------------------------------------------------
__global__ __launch_bounds__(256) void xw_split(
    const float* __restrict__ X,
    const bf16* __restrict__ Wh, const bf16* __restrict__ Wm, const bf16* __restrict__ Wl,
    const float* __restrict__ dnv, float* __restrict__ Z)
{
  __shared__ __align__(16) bf16 Xs[3][128 * 32];
  __shared__ __align__(16) bf16 Ws[3][128 * 32];

  const int t = threadIdx.x;
  const int w = t >> 6, l = t & 63;
  const int wr = w >> 1, wc = w & 1;
  const int lr = l & 15, q = l >> 4;
  const int r0 = blockIdx.x * 128;

  const int srow = t >> 1;          // 0..127
  const int soff = (t & 1) * 16;    // 0 or 16
  const int sbase = srow * 32 + soff;

  floatx4 acc[4][4];
#pragma unroll
  for (int i = 0; i < 4; ++i)
#pragma unroll
    for (int j = 0; j < 4; ++j) acc[i][j] = (floatx4)0.0f;

  const bf16* wsrc[3] = {Wh, Wm, Wl};

  for (int ks = 0; ks < 4; ++ks) {
    const int k0 = ks * 32;
    // global reads first
    float xv[16];
    const float* xsrc = X + (size_t)(r0 + srow) * 128 + k0 + soff;
#pragma unroll
    for (int i = 0; i < 16; i += 4) {
      floatx4 tmp = *(const floatx4*)(xsrc + i);
      xv[i] = tmp[0]; xv[i + 1] = tmp[1]; xv[i + 2] = tmp[2]; xv[i + 3] = tmp[3];
    }
    bf16x8 wv[3][2];
#pragma unroll
    for (int s = 0; s < 3; ++s) {
      const bf16* ws = wsrc[s] + (size_t)srow * 128 + k0 + soff;
      wv[s][0] = *(const bf16x8*)ws;
      wv[s][1] = *(const bf16x8*)(ws + 8);
    }
    // split X
    bf16x8 vh[2], vm[2], vl[2];
#pragma unroll
    for (int i = 0; i < 16; ++i) {
      float v = xv[i];
      bf16 h = (bf16)v; float r1 = v - (float)h;
      bf16 m = (bf16)r1; float r2 = r1 - (float)m;
      bf16 lo = (bf16)r2;
      vh[i >> 3][i & 7] = h; vm[i >> 3][i & 7] = m; vl[i >> 3][i & 7] = lo;
    }
    __syncthreads();
    *(bf16x8*)&Xs[0][sbase] = vh[0]; *(bf16x8*)&Xs[0][sbase + 8] = vh[1];
    *(bf16x8*)&Xs[1][sbase] = vm[0]; *(bf16x8*)&Xs[1][sbase + 8] = vm[1];
    *(bf16x8*)&Xs[2][sbase] = vl[0]; *(bf16x8*)&Xs[2][sbase + 8] = vl[1];
#pragma unroll
    for (int s = 0; s < 3; ++s) {
      *(bf16x8*)&Ws[s][sbase] = wv[s][0];
      *(bf16x8*)&Ws[s][sbase + 8] = wv[s][1];
    }
    __syncthreads();

    bf16x8 af[3][4], bfg[3][4];
#pragma unroll
    for (int s = 0; s < 3; ++s) {
#pragma unroll
      for (int mi = 0; mi < 4; ++mi)
        af[s][mi] = *(const bf16x8*)&Xs[s][(wr * 64 + mi * 16 + lr) * 32 + q * 8];
#pragma unroll
      for (int ni = 0; ni < 4; ++ni)
        bfg[s][ni] = *(const bf16x8*)&Ws[s][(wc * 64 + ni * 16 + lr) * 32 + q * 8];
    }
    const int sa[6] = {0, 0, 1, 1, 0, 2};
    const int sb[6] = {0, 1, 0, 1, 2, 0};
#pragma unroll
    for (int p = 0; p < 6; ++p)
#pragma unroll
      for (int mi = 0; mi < 4; ++mi)
#pragma unroll
        for (int ni = 0; ni < 4; ++ni)
          acc[mi][ni] = __builtin_amdgcn_mfma_f32_16x16x32_bf16(
              af[sa[p]][mi], bfg[sb[p]][ni], acc[mi][ni], 0, 0, 0);
  }

#pragma unroll
  for (int mi = 0; mi < 4; ++mi) {
#pragma unroll
    for (int ni = 0; ni < 4; ++ni) {
      const int col = wc * 64 + ni * 16 + lr;
      const int rowb = r0 + wr * 64 + mi * 16 + q * 4;
#pragma unroll
      for (int r = 0; r < 4; ++r)
        Z[(size_t)(rowb + r) * 128 + col] = dnv[rowb + r] * acc[mi][ni][r];
    }
  }
}

// ---------------------------------------------------------------------------
// Y[r,:] = sum_{j != r} A[r,j] * Z[j,:] + 2*Z[r,:]   (fp32, one block per row)
// ---------------------------------------------------------------------------
__global__ __launch_bounds__(256) void spmm_f32(
    const float* __restrict__ A, int lda,
    const float* __restrict__ Zs, float* __restrict__ Y, int n)
{
  int r = blockIdx.x;
  const float* arow = A + (size_t)r * lda;
  __shared__ int idxs[4096];
  __shared__ float avals[4096];
  __shared__ int cnt;
  __shared__ float part[128];
  int t = threadIdx.x;
  if (t == 0) cnt = 0;
  __syncthreads();
  for (int j = t; j < n; j += 256) {
    float v = arow[j];
    if (v != 0.f && j != r) {
      int p = atomicAdd(&cnt, 1);
      idxs[p] = j; avals[p] = v;
    }
  }
  __syncthreads();
  int m = cnt;
  int c = t & 127, half = t >> 7;
  float acc = (half == 0) ? 2.0f * Zs[(size_t)r * 128 + c] : 0.f;
  for (int p = half; p < m; p += 2)
    acc += avals[p] * Zs[(size_t)idxs[p] * 128 + c];
  if (half) part[c] = acc;
  __syncthreads();
  if (!half) Y[(size_t)r * 128 + c] = acc + part[c];
}

// ---------------------------------------------------------------------------
// small kernels
// ---------------------------------------------------------------------------
__global__ void pnorm_kernel(const float* __restrict__ pw, float* __restrict__ invp) {
  __shared__ float red[128];
  int t = threadIdx.x;
  for (int l = 0; l < 3; ++l) {
    float v = pw[l * 128 + t];
    red[t] = v * v; __syncthreads();
    for (int off = 64; off; off >>= 1) {
      if (t < off) red[t] += red[t + off];
      __syncthreads();
    }
    if (t == 0) invp[l] = 1.0f / sqrtf(red[0]);
    __syncthreads();
  }
}

// conv_w [7][k][c] fp32 -> transposed 3-way split [7][c][k] bf16
__global__ void split_w(const float* __restrict__ W, bf16* __restrict__ Wh,
                        bf16* __restrict__ Wm, bf16* __restrict__ Wl) {
  int idx = blockIdx.x * 256 + threadIdx.x;   // 7*128*128
  int l = idx >> 14, rem = idx & 16383, c = rem >> 7, k = rem & 127;
  float v = W[(l << 14) + (k << 7) + c];
  bf16 h = (bf16)v; float r1 = v - (float)h;
  bf16 m = (bf16)r1; float r2 = r1 - (float)m;
  Wh[idx] = h; Wm[idx] = m; Wl[idx] = (bf16)r2;
}

// dn[r] = rsqrt(sum_{c != r} A[r,c] + 2)
__global__ void dn_rows(const float* __restrict__ A, int lda, float* __restrict__ dn,
                        int n) {
  int r = blockIdx.x;
  const float* row = A + (size_t)r * lda;
  float sum = 0.f;
  for (int c = threadIdx.x; c < n; c += 256)
    if (c != r) sum += row[c];
  __shared__ float red[256];
  red[threadIdx.x] = sum; __syncthreads();
  for (int off = 128; off; off >>= 1) {
    if (threadIdx.x < off) red[threadIdx.x] += red[threadIdx.x + off];
    __syncthreads();
  }
  if (threadIdx.x == 0) dn[r] = 1.0f / sqrtf(red[0] + 2.0f);
}

__global__ void score_kernel(const float* __restrict__ x, const float* __restrict__ p,
                             const float* __restrict__ invp, float* __restrict__ s) {
  int wave = (blockIdx.x * 256 + threadIdx.x) >> 6;
  int l = threadIdx.x & 63;
  const float* xr = x + (size_t)wave * 128;
  float partial = xr[l] * p[l] + xr[l + 64] * p[l + 64];
  for (int off = 32; off; off >>= 1) partial += __shfl_down(partial, off, 64);
  if (l == 0) s[wave] = tanhf(partial * invp[0]);
}

// single block bitonic sort (descending) -> k-th largest
__global__ void kth_largest(const float* __restrict__ s, int n, int k,
                            float* __restrict__ out) {
  __shared__ float v[4096];
  int tid = threadIdx.x;
  for (int i = tid; i < n; i += 1024) v[i] = s[i];
  __syncthreads();
  for (int size2 = 2; size2 <= n; size2 <<= 1) {
    for (int stride = size2 >> 1; stride > 0; stride >>= 1) {
      for (int i = tid; i < n; i += 1024) {
        int j = i ^ stride;
        if (j > i) {
          float a = v[i], b = v[j];
          bool up = ((i & size2) == 0);
          if ((a < b) == up) { v[i] = b; v[j] = a; }
        }
      }
      __syncthreads();
    }
  }
  if (tid == 0) out[0] = v[k - 1];
}

// deterministic compaction: s>thr by ascending idx, then ties s==thr by ascending idx
__global__ void compact_kernel(const float* __restrict__ s, const float* __restrict__ thrp,
                               int n, int k, int* __restrict__ perm,
                               float* __restrict__ vals) {
  __shared__ int cg[1024], ce[1024];
  int tid = threadIdx.x;
  float thr = *thrp;
  int chunk = n >> 10;
  int beg = tid * chunk;
  int g = 0, e = 0;
  for (int i = 0; i < chunk; ++i) {
    float v = s[beg + i];
    g += (v > thr); e += (v == thr);
  }
  cg[tid] = g; ce[tid] = e; __syncthreads();
  for (int off = 1; off < 1024; off <<= 1) {
    int a = (tid >= off) ? cg[tid - off] : 0;
    int b = (tid >= off) ? ce[tid - off] : 0;
    __syncthreads();
    cg[tid] += a; ce[tid] += b;
    __syncthreads();
  }
  int total_gt = cg[1023];
  int pg = cg[tid] - g;
  int pe = ce[tid] - e;
  int need = k - total_gt;
  for (int i = 0; i < chunk; ++i) {
    float v = s[beg + i];
    if (v > thr) { perm[pg] = beg + i; vals[pg] = v; ++pg; }
    else if (v == thr) {
      if (pe < need) { perm[total_gt + pe] = beg + i; vals[total_gt + pe] = v; }
      ++pe;
    }
  }
}

// R[j,:] = (A + I)[perm[j], :] in bf16 (source diag garbage/zero -> substitute 1)
__global__ void gather_rows(const float* __restrict__ src, int lda,
                            const int* __restrict__ perm, bf16* __restrict__ R, int n) {
  int j = blockIdx.x;
  int r = perm[j];
  const float* s = src + (size_t)r * lda;
  bf16* o = R + (size_t)j * n;
  for (int c = threadIdx.x; c < n; c += 256)
    o[c] = (c == r) ? (bf16)1.0f : (bf16)s[c];
}

__global__ void pool_x(const float* __restrict__ res, const int* __restrict__ perm,
                       const float* __restrict__ vals, float* __restrict__ xp) {
  int j = blockIdx.x, c = threadIdx.x;
  xp[(size_t)j * 128 + c] = res[(size_t)perm[j] * 128 + c] * vals[j];
}

__global__ void scatter_add(float* __restrict__ xin, const float* __restrict__ up,
                            const int* __restrict__ perm) {
  int j = blockIdx.x, c = threadIdx.x;
  int r = perm[j];
  xin[(size_t)r * 128 + c] += up[(size_t)j * 128 + c];
}

// y = dn[r]*acc + bias; optional relu; store H; accumulate BN col stats
__global__ void gcn_post(const float* __restrict__ acc, const float* __restrict__ dn,
                         const float* __restrict__ bias, float* __restrict__ H,
                         float* __restrict__ stats, int relu) {
  int c = threadIdx.x;
  int r0 = blockIdx.x * 16;
  float b = bias[c];
  float s = 0.f, qq = 0.f;
  for (int i = 0; i < 16; ++i) {
    int r = r0 + i;
    float v = dn[r] * acc[(size_t)r * 128 + c] + b;
    if (relu) v = fmaxf(v, 0.f);
    H[(size_t)r * 128 + c] = v;
    s += v; qq += v * v;
  }
  atomicAdd(&stats[c], s);
  atomicAdd(&stats[128 + c], qq);
}

__global__ void bn_fin(const float* __restrict__ stats, const float* __restrict__ g,
                       const float* __restrict__ b, float* __restrict__ coef, int n) {
  int c = threadIdx.x;
  float m = stats[c] / n;
  float var = stats[128 + c] / n - m * m;
  float inv = 1.0f / sqrtf(var + 1e-5f);
  float sc = g[c] * inv;
  coef[c] = sc;
  coef[128 + c] = b[c] - m * sc;
}

__global__ void bn_apply(const float* __restrict__ H, const float* __restrict__ coef,
                         float* __restrict__ xout) {
  int r = blockIdx.x, c = threadIdx.x;
  xout[(size_t)r * 128 + c] = coef[c] * H[(size_t)r * 128 + c] + coef[128 + c];
}

// ---------------------------------------------------------------------------
extern "C" void kernel_launch(void* const* d_in, const int* in_sizes, int n_in,
                              void* d_out, int out_size, void* d_ws, size_t ws_size,
                              hipStream_t stream) {
  const float* x_in   = (const float*)d_in[0];
  const float* adj    = (const float*)d_in[1];
  const float* conv_w = (const float*)d_in[2];
  const float* conv_b = (const float*)d_in[3];
  const float* pool_w = (const float*)d_in[4];
  const float* bn_g   = (const float*)d_in[5];
  const float* bn_b   = (const float*)d_in[6];
  float* out = (float*)d_out;
  (void)in_sizes; (void)n_in; (void)out_size; (void)ws_size;

  char* p = (char*)d_ws;
  auto alloc = [&](size_t bytes) -> void* {
    void* r = (void*)p;
    p += (bytes + 255) & ~(size_t)255;
    return r;
  };
  float* A1f  = (float*)alloc(2048ull * 2048 * 4);
  float* A2f  = (float*)alloc(1024ull * 1024 * 4);
  float* A3f  = (float*)alloc(512ull * 512 * 4);
  bf16*  Rbuf = (bf16*)alloc(2048ull * 4096 * 2);
  float* Z    = (float*)alloc(4096ull * 128 * 4);
  float* Agg  = (float*)alloc(4096ull * 128 * 4);
  float* H    = (float*)alloc(4096ull * 128 * 4);
  float* res0 = (float*)alloc(4096ull * 128 * 4);
  float* res1 = (float*)alloc(2048ull * 128 * 4);
  float* res2 = (float*)alloc(1024ull * 128 * 4);
  float* Xp   = (float*)alloc(2048ull * 128 * 4);
  float* xin  = (float*)alloc(4096ull * 128 * 4);
  float* xb0  = (float*)alloc(512ull * 128 * 4);
  float* xb1  = (float*)alloc(1024ull * 128 * 4);
  float* xb2  = (float*)alloc(2048ull * 128 * 4);
  bf16*  Wh   = (bf16*)alloc(7ull * 16384 * 2);
  bf16*  Wm   = (bf16*)alloc(7ull * 16384 * 2);
  bf16*  Wl   = (bf16*)alloc(7ull * 16384 * 2);
  float* scores = (float*)alloc(4096 * 4);
  float* thrb = (float*)alloc(256);
  int* perm0 = (int*)alloc(2048 * 4);
  int* perm1 = (int*)alloc(1024 * 4);
  int* perm2 = (int*)alloc(512 * 4);
  float* vals0 = (float*)alloc(2048 * 4);
  float* vals1 = (float*)alloc(1024 * 4);
  float* vals2 = (float*)alloc(512 * 4);
  float* dn0 = (float*)alloc(4096 * 4);
  float* dn1 = (float*)alloc(2048 * 4);
  float* dn2 = (float*)alloc(1024 * 4);
  float* dn3 = (float*)alloc(512 * 4);
  float* invp = (float*)alloc(256);
  float* stats = (float*)alloc(1024);
  float* coef = (float*)alloc(1024);

  auto gcn = [&](int nr, const float* Asrc, int lda, const float* dnv, int layer,
                 const float* xsrc, float* xout, int relu) {
    xw_split<<<nr / 128, 256, 0, stream>>>(
        xsrc, Wh + layer * 16384, Wm + layer * 16384, Wl + layer * 16384, dnv, Z);
    spmm_f32<<<nr, 256, 0, stream>>>(Asrc, lda, Z, Agg, nr);
    hipMemsetAsync(stats, 0, 1024, stream);
    gcn_post<<<nr / 16, 128, 0, stream>>>(Agg, dnv, conv_b + layer * 128, H, stats, relu);
    bn_fin<<<1, 128, 0, stream>>>(stats, bn_g + layer * 128, bn_b + layer * 128, coef, nr);
    bn_apply<<<nr, 128, 0, stream>>>(H, coef, xout);
  };

  auto pool = [&](int lev, int n, const float* xprev, const float* Asrc, int lda,
                  float* Anew, float* dnNew, int* perm, float* vals, int splitZ) {
    int k = n / 2;
    score_kernel<<<n / 4, 256, 0, stream>>>(xprev, pool_w + (lev - 1) * 128,
                                            invp + (lev - 1), scores);
    kth_largest<<<1, 1024, 0, stream>>>(scores, n, k, thrb);
    compact_kernel<<<1, 1024, 0, stream>>>(scores, thrb, n, k, perm, vals);
    gather_rows<<<k, 256, 0, stream>>>(Asrc, lda, perm, Rbuf, n);
    hipMemsetAsync(Anew, 0, (size_t)k * k * 4, stream);
    gemm_nt_acc<<<dim3(k / 128, k / 128, splitZ), 256, 0, stream>>>(
        Rbuf, Rbuf, Anew, n, n, k, n / (splitZ * 32));
    dn_rows<<<k, 256, 0, stream>>>(Anew, k, dnNew, k);
    pool_x<<<k, 128, 0, stream>>>(xprev, perm, vals, Xp);
  };

  // ---- prep ----
  pnorm_kernel<<<1, 128, 0, stream>>>(pool_w, invp);
  split_w<<<448, 256, 0, stream>>>(conv_w, Wh, Wm, Wl);
  dn_rows<<<4096, 256, 0, stream>>>(adj, 4096, dn0, 4096);

  // ---- down ----
  gcn(4096, adj, 4096, dn0, 0, x_in, res0, 1);
  pool(1, 4096, res0, adj, 4096, A1f, dn1, perm0, vals0, 4);
  gcn(2048, A1f, 2048, dn1, 1, Xp, res1, 1);
  pool(2, 2048, res1, A1f, 2048, A2f, dn2, perm1, vals1, 4);
  gcn(1024, A2f, 1024, dn2, 2, Xp, res2, 1);
  pool(3, 1024, res2, A2f, 1024, A3f, dn3, perm2, vals2, 8);
  gcn(512, A3f, 512, dn3, 3, Xp, xb0, 1);

  // ---- up ----
  hipMemcpyAsync(xin, res2, 1024ull * 128 * 4, hipMemcpyDeviceToDevice, stream);
  scatter_add<<<512, 128, 0, stream>>>(xin, xb0, perm2);
  gcn(1024, A2f, 1024, dn2, 4, xin, xb1, 1);

  hipMemcpyAsync(xin, res1, 2048ull * 128 * 4, hipMemcpyDeviceToDevice, stream);
  scatter_add<<<1024, 128, 0, stream>>>(xin, xb1, perm1);
  gcn(2048, A1f, 2048, dn1, 5, xin, xb2, 1);

  hipMemcpyAsync(xin, res0, 4096ull * 128 * 4, hipMemcpyDeviceToDevice, stream);
  scatter_add<<<2048, 128, 0, stream>>>(xin, xb2, perm0);
  gcn(4096, adj, 4096, dn0, 6, xin, out, 0);
}

// Round 3
// 779.100 us; speedup vs baseline: 1.7292x; 1.7292x over previous
//
#include <hip/hip_runtime.h>
#include <cstdint>
#include <cstddef>

typedef __bf16 bf16;
typedef __bf16 bf16x8 __attribute__((ext_vector_type(8)));
typedef __bf16 bf16x4 __attribute__((ext_vector_type(4)));
typedef float floatx4 __attribute__((ext_vector_type(4)));

#define GLD16(gp, lp) __builtin_amdgcn_global_load_lds( \
    (const __attribute__((address_space(1))) void*)(gp), \
    (__attribute__((address_space(3))) void*)(lp), 16, 0, 0)

// ---------------------------------------------------------------------------
// NT GEMM (augment): C[M,N] += A[M,K] * B[N,K]^T, bf16 in, fp32 atomic accum.
// Exact for integer-valued inputs (products & sums < 2^24).
// ---------------------------------------------------------------------------
__global__ __launch_bounds__(256) void gemm_nt_acc(
    const bf16* __restrict__ A, const bf16* __restrict__ B, float* __restrict__ C,
    int lda, int ldb, int ldc, int kIters)
{
  __shared__ __align__(16) bf16 smem[2 * 128 * 32];
  bf16* As = smem;
  bf16* Bs = smem + 128 * 32;

  const int t = threadIdx.x;
  const int w = t >> 6;
  const int l = t & 63;
  const int wr = w >> 1, wc = w & 1;
  const int lr = l & 15, q = l >> 4;

  const int m0 = blockIdx.x * 128;
  const int n0 = blockIdx.y * 128;
  const int k0base = blockIdx.z * kIters * 32;

  const bf16* Ab = A + (size_t)m0 * lda + k0base;
  const bf16* Bb = B + (size_t)n0 * ldb + k0base;

  const int srow = t >> 2;
  const int schunk = (t & 3) * 8;

  floatx4 acc[4][4];
#pragma unroll
  for (int i = 0; i < 4; ++i)
#pragma unroll
    for (int j = 0; j < 4; ++j) acc[i][j] = (floatx4)0.0f;

  for (int kb = 0; kb < kIters; ++kb) {
    const int k0 = kb * 32;
    __syncthreads();
    GLD16(Ab + (size_t)srow * lda + k0 + schunk,        As + (size_t)t * 8);
    GLD16(Ab + (size_t)(srow + 64) * lda + k0 + schunk, As + (size_t)(t + 256) * 8);
    GLD16(Bb + (size_t)srow * ldb + k0 + schunk,        Bs + (size_t)t * 8);
    GLD16(Bb + (size_t)(srow + 64) * ldb + k0 + schunk, Bs + (size_t)(t + 256) * 8);
    __syncthreads();

    bf16x8 af[4], bfr[4];
#pragma unroll
    for (int mi = 0; mi < 4; ++mi)
      af[mi] = *(const bf16x8*)&As[(wr * 64 + mi * 16 + lr) * 32 + q * 8];
#pragma unroll
    for (int ni = 0; ni < 4; ++ni)
      bfr[ni] = *(const bf16x8*)&Bs[(wc * 64 + ni * 16 + lr) * 32 + q * 8];
#pragma unroll
    for (int mi = 0; mi < 4; ++mi)
#pragma unroll
      for (int ni = 0; ni < 4; ++ni)
        acc[mi][ni] = __builtin_amdgcn_mfma_f32_16x16x32_bf16(
            af[mi], bfr[ni], acc[mi][ni], 0, 0, 0);
  }

#pragma unroll
  for (int mi = 0; mi < 4; ++mi) {
#pragma unroll
    for (int ni = 0; ni < 4; ++ni) {
      const int col = n0 + wc * 64 + ni * 16 + lr;
      const int rowb = m0 + wr * 64 + mi * 16 + q * 4;
#pragma unroll
      for (int r = 0; r < 4; ++r)
        atomicAdd(&C[(size_t)(rowb + r) * ldc + col], acc[mi][ni][r]);
    }
  }
}

// ---------------------------------------------------------------------------
// Aggregation: Y[M,128] += A[M,K] (fp32, diag zeroed) @ Z[K,128]
// Z supplied as 3 transposed bf16 planes Zh/Zm/Zl [128][K] (Z = h+m+l).
// A split on the fly to hi/lo bf16 (lo skipped when aTwo==0: A exact in bf16).
// Terms: Ah*(Zh+Zm+Zl) (+ Al*(Zh+Zm)) -> ~2^-24 relative.
// Grid (M/128, splitK); atomic fp32 accumulate into Y.
// ---------------------------------------------------------------------------
__global__ __launch_bounds__(256) void agg_split(
    const float* __restrict__ A, int lda,
    const bf16* __restrict__ Zh, const bf16* __restrict__ Zm, const bf16* __restrict__ Zl,
    int ldz, float* __restrict__ Y, int kIters, int aTwo)
{
  __shared__ __align__(16) bf16 Ahs[128 * 32];
  __shared__ __align__(16) bf16 Als[128 * 32];
  __shared__ __align__(16) bf16 Zs[3][128 * 32];

  const int t = threadIdx.x;
  const int w = t >> 6, l = t & 63;
  const int wr = w >> 1, wc = w & 1;
  const int lr = l & 15, q = l >> 4;
  const int m0 = blockIdx.x * 128;
  const int k0base = blockIdx.y * kIters * 32;

  const int arow = t >> 1;          // 0..127
  const int acol = (t & 1) * 16;    // 0 or 16
  const int zrow = t >> 2;          // 0..63
  const int zchunk = (t & 3) * 8;

  floatx4 acc[4][4];
#pragma unroll
  for (int i = 0; i < 4; ++i)
#pragma unroll
    for (int j = 0; j < 4; ++j) acc[i][j] = (floatx4)0.0f;

  for (int kb = 0; kb < kIters; ++kb) {
    const int k0 = k0base + kb * 32;
    // global fp32 A reads (registers; no LDS hazard yet)
    const float* asrc = A + (size_t)(m0 + arow) * lda + k0 + acol;
    floatx4 av[4];
#pragma unroll
    for (int i = 0; i < 4; ++i) av[i] = *(const floatx4*)(asrc + i * 4);

    __syncthreads();
    GLD16(Zh + (size_t)zrow * ldz + k0 + zchunk,        Zs[0] + (size_t)t * 8);
    GLD16(Zh + (size_t)(zrow + 64) * ldz + k0 + zchunk, Zs[0] + (size_t)(t + 256) * 8);
    GLD16(Zm + (size_t)zrow * ldz + k0 + zchunk,        Zs[1] + (size_t)t * 8);
    GLD16(Zm + (size_t)(zrow + 64) * ldz + k0 + zchunk, Zs[1] + (size_t)(t + 256) * 8);
    GLD16(Zl + (size_t)zrow * ldz + k0 + zchunk,        Zs[2] + (size_t)t * 8);
    GLD16(Zl + (size_t)(zrow + 64) * ldz + k0 + zchunk, Zs[2] + (size_t)(t + 256) * 8);

    // split A (zeroing the true diagonal so it never enters low precision)
    bf16x8 ah[2], alo[2];
    const int grow = m0 + arow;
#pragma unroll
    for (int i = 0; i < 16; ++i) {
      float v = av[i >> 2][i & 3];
      if (k0 + acol + i == grow) v = 0.0f;
      bf16 h = (bf16)v;
      ah[i >> 3][i & 7] = h;
      alo[i >> 3][i & 7] = (bf16)(v - (float)h);
    }
    const int sbase = arow * 32 + acol;
    *(bf16x8*)&Ahs[sbase] = ah[0]; *(bf16x8*)&Ahs[sbase + 8] = ah[1];
    if (aTwo) { *(bf16x8*)&Als[sbase] = alo[0]; *(bf16x8*)&Als[sbase + 8] = alo[1]; }
    __syncthreads();

    bf16x8 afh[4], afl[4], bz[3][4];
#pragma unroll
    for (int mi = 0; mi < 4; ++mi)
      afh[mi] = *(const bf16x8*)&Ahs[(wr * 64 + mi * 16 + lr) * 32 + q * 8];
#pragma unroll
    for (int s = 0; s < 3; ++s)
#pragma unroll
      for (int ni = 0; ni < 4; ++ni)
        bz[s][ni] = *(const bf16x8*)&Zs[s][(wc * 64 + ni * 16 + lr) * 32 + q * 8];
#pragma unroll
    for (int s = 0; s < 3; ++s)
#pragma unroll
      for (int mi = 0; mi < 4; ++mi)
#pragma unroll
        for (int ni = 0; ni < 4; ++ni)
          acc[mi][ni] = __builtin_amdgcn_mfma_f32_16x16x32_bf16(
              afh[mi], bz[s][ni], acc[mi][ni], 0, 0, 0);
    if (aTwo) {
#pragma unroll
      for (int mi = 0; mi < 4; ++mi)
        afl[mi] = *(const bf16x8*)&Als[(wr * 64 + mi * 16 + lr) * 32 + q * 8];
#pragma unroll
      for (int s = 0; s < 2; ++s)
#pragma unroll
        for (int mi = 0; mi < 4; ++mi)
#pragma unroll
          for (int ni = 0; ni < 4; ++ni)
            acc[mi][ni] = __builtin_amdgcn_mfma_f32_16x16x32_bf16(
                afl[mi], bz[s][ni], acc[mi][ni], 0, 0, 0);
    }
  }

#pragma unroll
  for (int mi = 0; mi < 4; ++mi) {
#pragma unroll
    for (int ni = 0; ni < 4; ++ni) {
      const int col = wc * 64 + ni * 16 + lr;
      const int rowb = m0 + wr * 64 + mi * 16 + q * 4;
#pragma unroll
      for (int r = 0; r < 4; ++r)
        atomicAdd(&Y[(size_t)(rowb + r) * 128 + col], acc[mi][ni][r]);
    }
  }
}

// ---------------------------------------------------------------------------
// Z[nr,128] = dn ⊙ (X @ W), fp32-accurate via 3-way bf16 split, 6-term MFMA.
// Also emits Z transposed as 3 bf16 planes [128][ldz] for the aggregation.
// ---------------------------------------------------------------------------
__global__ __launch_bounds__(256) void xw_split(
    const float* __restrict__ X,
    const bf16* __restrict__ Wh, const bf16* __restrict__ Wm, const bf16* __restrict__ Wl,
    const float* __restrict__ dnv, float* __restrict__ Z,
    bf16* __restrict__ Zht, bf16* __restrict__ Zmt, bf16* __restrict__ Zlt, int ldz)
{
  __shared__ __align__(16) bf16 Xs[3][128 * 32];
  __shared__ __align__(16) bf16 Ws[3][128 * 32];

  const int t = threadIdx.x;
  const int w = t >> 6, l = t & 63;
  const int wr = w >> 1, wc = w & 1;
  const int lr = l & 15, q = l >> 4;
  const int r0 = blockIdx.x * 128;

  const int srow = t >> 1;
  const int soff = (t & 1) * 16;
  const int sbase = srow * 32 + soff;

  floatx4 acc[4][4];
#pragma unroll
  for (int i = 0; i < 4; ++i)
#pragma unroll
    for (int j = 0; j < 4; ++j) acc[i][j] = (floatx4)0.0f;

  const bf16* wsrc[3] = {Wh, Wm, Wl};

  for (int ks = 0; ks < 4; ++ks) {
    const int k0 = ks * 32;
    float xv[16];
    const float* xsrc = X + (size_t)(r0 + srow) * 128 + k0 + soff;
#pragma unroll
    for (int i = 0; i < 16; i += 4) {
      floatx4 tmp = *(const floatx4*)(xsrc + i);
      xv[i] = tmp[0]; xv[i + 1] = tmp[1]; xv[i + 2] = tmp[2]; xv[i + 3] = tmp[3];
    }
    bf16x8 wv[3][2];
#pragma unroll
    for (int s = 0; s < 3; ++s) {
      const bf16* ws = wsrc[s] + (size_t)srow * 128 + k0 + soff;
      wv[s][0] = *(const bf16x8*)ws;
      wv[s][1] = *(const bf16x8*)(ws + 8);
    }
    bf16x8 vh[2], vm[2], vl[2];
#pragma unroll
    for (int i = 0; i < 16; ++i) {
      float v = xv[i];
      bf16 h = (bf16)v; float r1 = v - (float)h;
      bf16 m = (bf16)r1; float r2 = r1 - (float)m;
      bf16 lo = (bf16)r2;
      vh[i >> 3][i & 7] = h; vm[i >> 3][i & 7] = m; vl[i >> 3][i & 7] = lo;
    }
    __syncthreads();
    *(bf16x8*)&Xs[0][sbase] = vh[0]; *(bf16x8*)&Xs[0][sbase + 8] = vh[1];
    *(bf16x8*)&Xs[1][sbase] = vm[0]; *(bf16x8*)&Xs[1][sbase + 8] = vm[1];
    *(bf16x8*)&Xs[2][sbase] = vl[0]; *(bf16x8*)&Xs[2][sbase + 8] = vl[1];
#pragma unroll
    for (int s = 0; s < 3; ++s) {
      *(bf16x8*)&Ws[s][sbase] = wv[s][0];
      *(bf16x8*)&Ws[s][sbase + 8] = wv[s][1];
    }
    __syncthreads();

    bf16x8 af[3][4], bfg[3][4];
#pragma unroll
    for (int s = 0; s < 3; ++s) {
#pragma unroll
      for (int mi = 0; mi < 4; ++mi)
        af[s][mi] = *(const bf16x8*)&Xs[s][(wr * 64 + mi * 16 + lr) * 32 + q * 8];
#pragma unroll
      for (int ni = 0; ni < 4; ++ni)
        bfg[s][ni] = *(const bf16x8*)&Ws[s][(wc * 64 + ni * 16 + lr) * 32 + q * 8];
    }
    const int sa[6] = {0, 0, 1, 1, 0, 2};
    const int sb[6] = {0, 1, 0, 1, 2, 0};
#pragma unroll
    for (int p = 0; p < 6; ++p)
#pragma unroll
      for (int mi = 0; mi < 4; ++mi)
#pragma unroll
        for (int ni = 0; ni < 4; ++ni)
          acc[mi][ni] = __builtin_amdgcn_mfma_f32_16x16x32_bf16(
              af[sa[p]][mi], bfg[sb[p]][ni], acc[mi][ni], 0, 0, 0);
  }

#pragma unroll
  for (int mi = 0; mi < 4; ++mi) {
    const int rowb = r0 + wr * 64 + mi * 16 + q * 4;
    float dnr[4];
#pragma unroll
    for (int r = 0; r < 4; ++r) dnr[r] = dnv[rowb + r];
#pragma unroll
    for (int ni = 0; ni < 4; ++ni) {
      const int col = wc * 64 + ni * 16 + lr;
      bf16x4 h4, m4, l4;
#pragma unroll
      for (int r = 0; r < 4; ++r) {
        float v = dnr[r] * acc[mi][ni][r];
        Z[(size_t)(rowb + r) * 128 + col] = v;
        bf16 h = (bf16)v; float r1 = v - (float)h;
        bf16 m = (bf16)r1; float r2 = r1 - (float)m;
        h4[r] = h; m4[r] = m; l4[r] = (bf16)r2;
      }
      *(bf16x4*)&Zht[(size_t)col * ldz + rowb] = h4;
      *(bf16x4*)&Zmt[(size_t)col * ldz + rowb] = m4;
      *(bf16x4*)&Zlt[(size_t)col * ldz + rowb] = l4;
    }
  }
}

// ---------------------------------------------------------------------------
// small kernels
// ---------------------------------------------------------------------------
__global__ void pnorm_kernel(const float* __restrict__ pw, float* __restrict__ invp) {
  __shared__ float red[128];
  int t = threadIdx.x;
  for (int l = 0; l < 3; ++l) {
    float v = pw[l * 128 + t];
    red[t] = v * v; __syncthreads();
    for (int off = 64; off; off >>= 1) {
      if (t < off) red[t] += red[t + off];
      __syncthreads();
    }
    if (t == 0) invp[l] = 1.0f / sqrtf(red[0]);
    __syncthreads();
  }
}

// conv_w [7][k][c] fp32 -> transposed 3-way split [7][c][k] bf16
__global__ void split_w(const float* __restrict__ W, bf16* __restrict__ Wh,
                        bf16* __restrict__ Wm, bf16* __restrict__ Wl) {
  int idx = blockIdx.x * 256 + threadIdx.x;
  int l = idx >> 14, rem = idx & 16383, c = rem >> 7, k = rem & 127;
  float v = W[(l << 14) + (k << 7) + c];
  bf16 h = (bf16)v; float r1 = v - (float)h;
  bf16 m = (bf16)r1; float r2 = r1 - (float)m;
  Wh[idx] = h; Wm[idx] = m; Wl[idx] = (bf16)r2;
}

// dn[r] = rsqrt(sum_{c != r} A[r,c] + 2)
__global__ void dn_rows(const float* __restrict__ A, int lda, float* __restrict__ dn,
                        int n) {
  int r = blockIdx.x;
  const float* row = A + (size_t)r * lda;
  float sum = 0.f;
  for (int c = threadIdx.x; c < n; c += 256)
    if (c != r) sum += row[c];
  __shared__ float red[256];
  red[threadIdx.x] = sum; __syncthreads();
  for (int off = 128; off; off >>= 1) {
    if (threadIdx.x < off) red[threadIdx.x] += red[threadIdx.x + off];
    __syncthreads();
  }
  if (threadIdx.x == 0) dn[r] = 1.0f / sqrtf(red[0] + 2.0f);
}

__global__ void score_kernel(const float* __restrict__ x, const float* __restrict__ p,
                             const float* __restrict__ invp, float* __restrict__ s) {
  int wave = (blockIdx.x * 256 + threadIdx.x) >> 6;
  int l = threadIdx.x & 63;
  const float* xr = x + (size_t)wave * 128;
  float partial = xr[l] * p[l] + xr[l + 64] * p[l + 64];
  for (int off = 32; off; off >>= 1) partial += __shfl_down(partial, off, 64);
  if (l == 0) s[wave] = tanhf(partial * invp[0]);
}

__global__ void kth_largest(const float* __restrict__ s, int n, int k,
                            float* __restrict__ out) {
  __shared__ float v[4096];
  int tid = threadIdx.x;
  for (int i = tid; i < n; i += 1024) v[i] = s[i];
  __syncthreads();
  for (int size2 = 2; size2 <= n; size2 <<= 1) {
    for (int stride = size2 >> 1; stride > 0; stride >>= 1) {
      for (int i = tid; i < n; i += 1024) {
        int j = i ^ stride;
        if (j > i) {
          float a = v[i], b = v[j];
          bool up = ((i & size2) == 0);
          if ((a < b) == up) { v[i] = b; v[j] = a; }
        }
      }
      __syncthreads();
    }
  }
  if (tid == 0) out[0] = v[k - 1];
}

__global__ void compact_kernel(const float* __restrict__ s, const float* __restrict__ thrp,
                               int n, int k, int* __restrict__ perm,
                               float* __restrict__ vals) {
  __shared__ int cg[1024], ce[1024];
  int tid = threadIdx.x;
  float thr = *thrp;
  int chunk = n >> 10;
  int beg = tid * chunk;
  int g = 0, e = 0;
  for (int i = 0; i < chunk; ++i) {
    float v = s[beg + i];
    g += (v > thr); e += (v == thr);
  }
  cg[tid] = g; ce[tid] = e; __syncthreads();
  for (int off = 1; off < 1024; off <<= 1) {
    int a = (tid >= off) ? cg[tid - off] : 0;
    int b = (tid >= off) ? ce[tid - off] : 0;
    __syncthreads();
    cg[tid] += a; ce[tid] += b;
    __syncthreads();
  }
  int total_gt = cg[1023];
  int pg = cg[tid] - g;
  int pe = ce[tid] - e;
  int need = k - total_gt;
  for (int i = 0; i < chunk; ++i) {
    float v = s[beg + i];
    if (v > thr) { perm[pg] = beg + i; vals[pg] = v; ++pg; }
    else if (v == thr) {
      if (pe < need) { perm[total_gt + pe] = beg + i; vals[total_gt + pe] = v; }
      ++pe;
    }
  }
}

// R[j,:] = (A + I)[perm[j], :] in bf16 (diag substitute 1)
__global__ void gather_rows(const float* __restrict__ src, int lda,
                            const int* __restrict__ perm, bf16* __restrict__ R, int n) {
  int j = blockIdx.x;
  int r = perm[j];
  const float* s = src + (size_t)r * lda;
  bf16* o = R + (size_t)j * n;
  for (int c = threadIdx.x; c < n; c += 256)
    o[c] = (c == r) ? (bf16)1.0f : (bf16)s[c];
}

__global__ void pool_x(const float* __restrict__ res, const int* __restrict__ perm,
                       const float* __restrict__ vals, float* __restrict__ xp) {
  int j = blockIdx.x, c = threadIdx.x;
  xp[(size_t)j * 128 + c] = res[(size_t)perm[j] * 128 + c] * vals[j];
}

__global__ void scatter_add(float* __restrict__ xin, const float* __restrict__ up,
                            const int* __restrict__ perm) {
  int j = blockIdx.x, c = threadIdx.x;
  int r = perm[j];
  xin[(size_t)r * 128 + c] += up[(size_t)j * 128 + c];
}

// y = dn[r]*(acc + 2*Z) + bias; optional relu; store H; accumulate BN col stats
__global__ void gcn_post(const float* __restrict__ acc, const float* __restrict__ Zf,
                         const float* __restrict__ dn, const float* __restrict__ bias,
                         float* __restrict__ H, float* __restrict__ stats, int relu) {
  int c = threadIdx.x;
  int r0 = blockIdx.x * 16;
  float b = bias[c];
  float s = 0.f, qq = 0.f;
  for (int i = 0; i < 16; ++i) {
    int r = r0 + i;
    float v = dn[r] * (acc[(size_t)r * 128 + c] + 2.0f * Zf[(size_t)r * 128 + c]) + b;
    if (relu) v = fmaxf(v, 0.f);
    H[(size_t)r * 128 + c] = v;
    s += v; qq += v * v;
  }
  atomicAdd(&stats[c], s);
  atomicAdd(&stats[128 + c], qq);
}

__global__ void bn_fin(const float* __restrict__ stats, const float* __restrict__ g,
                       const float* __restrict__ b, float* __restrict__ coef, int n) {
  int c = threadIdx.x;
  float m = stats[c] / n;
  float var = stats[128 + c] / n - m * m;
  float inv = 1.0f / sqrtf(var + 1e-5f);
  float sc = g[c] * inv;
  coef[c] = sc;
  coef[128 + c] = b[c] - m * sc;
}

__global__ void bn_apply(const float* __restrict__ H, const float* __restrict__ coef,
                         float* __restrict__ xout) {
  int r = blockIdx.x, c = threadIdx.x;
  xout[(size_t)r * 128 + c] = coef[c] * H[(size_t)r * 128 + c] + coef[128 + c];
}

// ---------------------------------------------------------------------------
extern "C" void kernel_launch(void* const* d_in, const int* in_sizes, int n_in,
                              void* d_out, int out_size, void* d_ws, size_t ws_size,
                              hipStream_t stream) {
  const float* x_in   = (const float*)d_in[0];
  const float* adj    = (const float*)d_in[1];
  const float* conv_w = (const float*)d_in[2];
  const float* conv_b = (const float*)d_in[3];
  const float* pool_w = (const float*)d_in[4];
  const float* bn_g   = (const float*)d_in[5];
  const float* bn_b   = (const float*)d_in[6];
  float* out = (float*)d_out;
  (void)in_sizes; (void)n_in; (void)out_size; (void)ws_size;

  char* p = (char*)d_ws;
  auto alloc = [&](size_t bytes) -> void* {
    void* r = (void*)p;
    p += (bytes + 255) & ~(size_t)255;
    return r;
  };
  float* A1f  = (float*)alloc(2048ull * 2048 * 4);
  float* A2f  = (float*)alloc(1024ull * 1024 * 4);
  float* A3f  = (float*)alloc(512ull * 512 * 4);
  bf16*  Rbuf = (bf16*)alloc(2048ull * 4096 * 2);
  float* Z    = (float*)alloc(4096ull * 128 * 4);
  bf16*  Zht  = (bf16*)alloc(128ull * 4096 * 2);
  bf16*  Zmt  = (bf16*)alloc(128ull * 4096 * 2);
  bf16*  Zlt  = (bf16*)alloc(128ull * 4096 * 2);
  float* Agg  = (float*)alloc(4096ull * 128 * 4);
  float* H    = (float*)alloc(4096ull * 128 * 4);
  float* res0 = (float*)alloc(4096ull * 128 * 4);
  float* res1 = (float*)alloc(2048ull * 128 * 4);
  float* res2 = (float*)alloc(1024ull * 128 * 4);
  float* Xp   = (float*)alloc(2048ull * 128 * 4);
  float* xin  = (float*)alloc(4096ull * 128 * 4);
  float* xb0  = (float*)alloc(512ull * 128 * 4);
  float* xb1  = (float*)alloc(1024ull * 128 * 4);
  float* xb2  = (float*)alloc(2048ull * 128 * 4);
  bf16*  Wh   = (bf16*)alloc(7ull * 16384 * 2);
  bf16*  Wm   = (bf16*)alloc(7ull * 16384 * 2);
  bf16*  Wl   = (bf16*)alloc(7ull * 16384 * 2);
  float* scores = (float*)alloc(4096 * 4);
  float* thrb = (float*)alloc(256);
  int* perm0 = (int*)alloc(2048 * 4);
  int* perm1 = (int*)alloc(1024 * 4);
  int* perm2 = (int*)alloc(512 * 4);
  float* vals0 = (float*)alloc(2048 * 4);
  float* vals1 = (float*)alloc(1024 * 4);
  float* vals2 = (float*)alloc(512 * 4);
  float* dn0 = (float*)alloc(4096 * 4);
  float* dn1 = (float*)alloc(2048 * 4);
  float* dn2 = (float*)alloc(1024 * 4);
  float* dn3 = (float*)alloc(512 * 4);
  float* invp = (float*)alloc(256);
  float* stats = (float*)alloc(1024);
  float* coef = (float*)alloc(1024);

  auto gcn = [&](int nr, const float* Asrc, int lda, const float* dnv, int layer,
                 const float* xsrc, float* xout, int relu, int aTwo) {
    xw_split<<<nr / 128, 256, 0, stream>>>(
        xsrc, Wh + layer * 16384, Wm + layer * 16384, Wl + layer * 16384, dnv,
        Z, Zht, Zmt, Zlt, nr);
    hipMemsetAsync(Agg, 0, (size_t)nr * 128 * 4, stream);
    agg_split<<<dim3(nr / 128, 8), 256, 0, stream>>>(
        Asrc, lda, Zht, Zmt, Zlt, nr, Agg, nr / 256, aTwo);
    hipMemsetAsync(stats, 0, 1024, stream);
    gcn_post<<<nr / 16, 128, 0, stream>>>(Agg, Z, dnv, conv_b + layer * 128, H, stats, relu);
    bn_fin<<<1, 128, 0, stream>>>(stats, bn_g + layer * 128, bn_b + layer * 128, coef, nr);
    bn_apply<<<nr, 128, 0, stream>>>(H, coef, xout);
  };

  auto pool = [&](int lev, int n, const float* xprev, const float* Asrc, int lda,
                  float* Anew, float* dnNew, int* perm, float* vals, int splitZ) {
    int k = n / 2;
    score_kernel<<<n / 4, 256, 0, stream>>>(xprev, pool_w + (lev - 1) * 128,
                                            invp + (lev - 1), scores);
    kth_largest<<<1, 1024, 0, stream>>>(scores, n, k, thrb);
    compact_kernel<<<1, 1024, 0, stream>>>(scores, thrb, n, k, perm, vals);
    gather_rows<<<k, 256, 0, stream>>>(Asrc, lda, perm, Rbuf, n);
    hipMemsetAsync(Anew, 0, (size_t)k * k * 4, stream);
    gemm_nt_acc<<<dim3(k / 128, k / 128, splitZ), 256, 0, stream>>>(
        Rbuf, Rbuf, Anew, n, n, k, n / (splitZ * 32));
    dn_rows<<<k, 256, 0, stream>>>(Anew, k, dnNew, k);
    pool_x<<<k, 128, 0, stream>>>(xprev, perm, vals, Xp);
  };

  // ---- prep ----
  pnorm_kernel<<<1, 128, 0, stream>>>(pool_w, invp);
  split_w<<<448, 256, 0, stream>>>(conv_w, Wh, Wm, Wl);
  dn_rows<<<4096, 256, 0, stream>>>(adj, 4096, dn0, 4096);

  // ---- down ----  (aTwo: 0 when off-diag entries exact in one bf16 plane)
  gcn(4096, adj, 4096, dn0, 0, x_in, res0, 1, 0);
  pool(1, 4096, res0, adj, 4096, A1f, dn1, perm0, vals0, 4);
  gcn(2048, A1f, 2048, dn1, 1, Xp, res1, 1, 0);
  pool(2, 2048, res1, A1f, 2048, A2f, dn2, perm1, vals1, 4);
  gcn(1024, A2f, 1024, dn2, 2, Xp, res2, 1, 1);
  pool(3, 1024, res2, A2f, 1024, A3f, dn3, perm2, vals2, 8);
  gcn(512, A3f, 512, dn3, 3, Xp, xb0, 1, 1);

  // ---- up ----
  hipMemcpyAsync(xin, res2, 1024ull * 128 * 4, hipMemcpyDeviceToDevice, stream);
  scatter_add<<<512, 128, 0, stream>>>(xin, xb0, perm2);
  gcn(1024, A2f, 1024, dn2, 4, xin, xb1, 1, 1);

  hipMemcpyAsync(xin, res1, 2048ull * 128 * 4, hipMemcpyDeviceToDevice, stream);
  scatter_add<<<1024, 128, 0, stream>>>(xin, xb1, perm1);
  gcn(2048, A1f, 2048, dn1, 5, xin, xb2, 1, 0);

  hipMemcpyAsync(xin, res0, 4096ull * 128 * 4, hipMemcpyDeviceToDevice, stream);
  scatter_add<<<2048, 128, 0, stream>>>(xin, xb2, perm0);
  gcn(4096, adj, 4096, dn0, 6, xin, out, 0, 0);
}

// Round 4
// 743.532 us; speedup vs baseline: 1.8119x; 1.0478x over previous
//
#include <hip/hip_runtime.h>
#include <cstdint>
#include <cstddef>

typedef __bf16 bf16;
typedef __bf16 bf16x8 __attribute__((ext_vector_type(8)));
typedef __bf16 bf16x4 __attribute__((ext_vector_type(4)));
typedef float floatx4 __attribute__((ext_vector_type(4)));

#define GLD16(gp, lp) __builtin_amdgcn_global_load_lds( \
    (const __attribute__((address_space(1))) void*)(gp), \
    (__attribute__((address_space(3))) void*)(lp), 16, 0, 0)

// ---------------------------------------------------------------------------
// Symmetric augment GEMM: upper-tri 128x128 block pairs of C = R * R^T.
// R [k x n] bf16. Per (pair, z) output slice stored densely (no atomics):
// Cs[(z*pairs + pair)*16384 + rl*128 + cl]. Exact for integer inputs.
// ---------------------------------------------------------------------------
__global__ __launch_bounds__(256) void gemm_sym(
    const bf16* __restrict__ R, float* __restrict__ Cs,
    int n /*lda = K*/, int kIters, int G)
{
  __shared__ __align__(16) bf16 smem[2 * 128 * 32];
  bf16* As = smem;
  bf16* Bs = smem + 128 * 32;

  // decode upper-tri pair
  int rem = blockIdx.x, bm = 0;
  while (rem >= G - bm) { rem -= G - bm; ++bm; }
  const int bn = bm + rem;
  const int m0 = bm * 128, n0 = bn * 128;

  const int t = threadIdx.x;
  const int w = t >> 6, l = t & 63;
  const int wr = w >> 1, wc = w & 1;
  const int lr = l & 15, q = l >> 4;
  const int k0base = blockIdx.y * kIters * 32;

  const bf16* Ab = R + (size_t)m0 * n + k0base;
  const bf16* Bb = R + (size_t)n0 * n + k0base;
  const int srow = t >> 2;
  const int schunk = (t & 3) * 8;

  floatx4 acc[4][4];
#pragma unroll
  for (int i = 0; i < 4; ++i)
#pragma unroll
    for (int j = 0; j < 4; ++j) acc[i][j] = (floatx4)0.0f;

  for (int kb = 0; kb < kIters; ++kb) {
    const int k0 = kb * 32;
    __syncthreads();
    GLD16(Ab + (size_t)srow * n + k0 + schunk,        As + (size_t)t * 8);
    GLD16(Ab + (size_t)(srow + 64) * n + k0 + schunk, As + (size_t)(t + 256) * 8);
    GLD16(Bb + (size_t)srow * n + k0 + schunk,        Bs + (size_t)t * 8);
    GLD16(Bb + (size_t)(srow + 64) * n + k0 + schunk, Bs + (size_t)(t + 256) * 8);
    __syncthreads();

    bf16x8 af[4], bfr[4];
#pragma unroll
    for (int mi = 0; mi < 4; ++mi)
      af[mi] = *(const bf16x8*)&As[(wr * 64 + mi * 16 + lr) * 32 + q * 8];
#pragma unroll
    for (int ni = 0; ni < 4; ++ni)
      bfr[ni] = *(const bf16x8*)&Bs[(wc * 64 + ni * 16 + lr) * 32 + q * 8];
#pragma unroll
    for (int mi = 0; mi < 4; ++mi)
#pragma unroll
      for (int ni = 0; ni < 4; ++ni)
        acc[mi][ni] = __builtin_amdgcn_mfma_f32_16x16x32_bf16(
            af[mi], bfr[ni], acc[mi][ni], 0, 0, 0);
  }

  float* cout = Cs + ((size_t)blockIdx.y * gridDim.x + blockIdx.x) * 16384;
#pragma unroll
  for (int mi = 0; mi < 4; ++mi)
#pragma unroll
    for (int ni = 0; ni < 4; ++ni) {
      const int cl = wc * 64 + ni * 16 + lr;
      const int rb = wr * 64 + mi * 16 + q * 4;
#pragma unroll
      for (int r = 0; r < 4; ++r)
        cout[(size_t)(rb + r) * 128 + cl] = acc[mi][ni][r];
    }
}

// Sum split-K slices, write A (bf16 and/or fp32) with symmetric mirror, diag=0.
__global__ void sym_post(const float* __restrict__ Cs, bf16* __restrict__ Abf,
                         float* __restrict__ Af, int k, int G, int pairs, int nz)
{
  int rem = blockIdx.x, bm = 0;
  while (rem >= G - bm) { rem -= G - bm; ++bm; }
  const int bn = bm + rem;
  const int i = threadIdx.x;           // 0..127 row within bm block
  const int r = bm * 128 + i;
  const float* base = Cs + (size_t)blockIdx.x * 16384 + (size_t)i * 128;

  for (int jc = 0; jc < 128; jc += 16) {
    float v[16];
#pragma unroll
    for (int e = 0; e < 16; ++e) v[e] = base[jc + e];
    for (int z = 1; z < nz; ++z) {
      const float* b2 = base + (size_t)z * pairs * 16384;
#pragma unroll
      for (int e = 0; e < 16; ++e) v[e] += b2[jc + e];
    }
#pragma unroll
    for (int e = 0; e < 16; ++e) {
      const int c = bn * 128 + jc + e;
      const float val = (c == r) ? 0.0f : v[e];
      if (Abf) Abf[(size_t)r * k + c] = (bf16)val;
      if (Af)  Af[(size_t)r * k + c] = val;
      if (bm != bn) {
        if (Abf) Abf[(size_t)c * k + r] = (bf16)val;
        if (Af)  Af[(size_t)c * k + r] = val;
      }
    }
  }
}

// ---------------------------------------------------------------------------
// Aggregation (exact-int A in bf16): Y[M,128] += A[M,K] @ Z[K,128]
// Z as 3 transposed bf16 planes [128][K]; 3-term MFMA; atomic fp32 accum.
// A diag must be stored 0.
// ---------------------------------------------------------------------------
__global__ __launch_bounds__(256) void agg_bf(
    const bf16* __restrict__ A, int lda,
    const bf16* __restrict__ Zh, const bf16* __restrict__ Zm, const bf16* __restrict__ Zl,
    int ldz, float* __restrict__ Y, int kIters)
{
  __shared__ __align__(16) bf16 As[128 * 32];
  __shared__ __align__(16) bf16 Zs[3][128 * 32];

  const int t = threadIdx.x;
  const int w = t >> 6, l = t & 63;
  const int wr = w >> 1, wc = w & 1;
  const int lr = l & 15, q = l >> 4;
  const int m0 = blockIdx.x * 128;
  const int k0base = blockIdx.y * kIters * 32;

  const int srow = t >> 2;
  const int schunk = (t & 3) * 8;

  floatx4 acc[4][4];
#pragma unroll
  for (int i = 0; i < 4; ++i)
#pragma unroll
    for (int j = 0; j < 4; ++j) acc[i][j] = (floatx4)0.0f;

  for (int kb = 0; kb < kIters; ++kb) {
    const int k0 = k0base + kb * 32;
    __syncthreads();
    GLD16(A + (size_t)(m0 + srow) * lda + k0 + schunk,        As + (size_t)t * 8);
    GLD16(A + (size_t)(m0 + srow + 64) * lda + k0 + schunk,   As + (size_t)(t + 256) * 8);
    GLD16(Zh + (size_t)srow * ldz + k0 + schunk,        Zs[0] + (size_t)t * 8);
    GLD16(Zh + (size_t)(srow + 64) * ldz + k0 + schunk, Zs[0] + (size_t)(t + 256) * 8);
    GLD16(Zm + (size_t)srow * ldz + k0 + schunk,        Zs[1] + (size_t)t * 8);
    GLD16(Zm + (size_t)(srow + 64) * ldz + k0 + schunk, Zs[1] + (size_t)(t + 256) * 8);
    GLD16(Zl + (size_t)srow * ldz + k0 + schunk,        Zs[2] + (size_t)t * 8);
    GLD16(Zl + (size_t)(srow + 64) * ldz + k0 + schunk, Zs[2] + (size_t)(t + 256) * 8);
    __syncthreads();

    bf16x8 af[4], bz[3][4];
#pragma unroll
    for (int mi = 0; mi < 4; ++mi)
      af[mi] = *(const bf16x8*)&As[(wr * 64 + mi * 16 + lr) * 32 + q * 8];
#pragma unroll
    for (int s = 0; s < 3; ++s)
#pragma unroll
      for (int ni = 0; ni < 4; ++ni)
        bz[s][ni] = *(const bf16x8*)&Zs[s][(wc * 64 + ni * 16 + lr) * 32 + q * 8];
#pragma unroll
    for (int s = 0; s < 3; ++s)
#pragma unroll
      for (int mi = 0; mi < 4; ++mi)
#pragma unroll
        for (int ni = 0; ni < 4; ++ni)
          acc[mi][ni] = __builtin_amdgcn_mfma_f32_16x16x32_bf16(
              af[mi], bz[s][ni], acc[mi][ni], 0, 0, 0);
  }

#pragma unroll
  for (int mi = 0; mi < 4; ++mi)
#pragma unroll
    for (int ni = 0; ni < 4; ++ni) {
      const int col = wc * 64 + ni * 16 + lr;
      const int rowb = m0 + wr * 64 + mi * 16 + q * 4;
#pragma unroll
      for (int r = 0; r < 4; ++r)
        atomicAdd(&Y[(size_t)(rowb + r) * 128 + col], acc[mi][ni][r]);
    }
}

// ---------------------------------------------------------------------------
// Aggregation (fp32 A, on-the-fly 2-plane split, diag zeroed by index):
// for levels whose A entries exceed bf16-exact range.
// ---------------------------------------------------------------------------
__global__ __launch_bounds__(256) void agg_split(
    const float* __restrict__ A, int lda,
    const bf16* __restrict__ Zh, const bf16* __restrict__ Zm, const bf16* __restrict__ Zl,
    int ldz, float* __restrict__ Y, int kIters, int aTwo)
{
  __shared__ __align__(16) bf16 Ahs[128 * 32];
  __shared__ __align__(16) bf16 Als[128 * 32];
  __shared__ __align__(16) bf16 Zs[3][128 * 32];

  const int t = threadIdx.x;
  const int w = t >> 6, l = t & 63;
  const int wr = w >> 1, wc = w & 1;
  const int lr = l & 15, q = l >> 4;
  const int m0 = blockIdx.x * 128;
  const int k0base = blockIdx.y * kIters * 32;

  const int arow = t >> 1;
  const int acol = (t & 1) * 16;
  const int zrow = t >> 2;
  const int zchunk = (t & 3) * 8;

  floatx4 acc[4][4];
#pragma unroll
  for (int i = 0; i < 4; ++i)
#pragma unroll
    for (int j = 0; j < 4; ++j) acc[i][j] = (floatx4)0.0f;

  for (int kb = 0; kb < kIters; ++kb) {
    const int k0 = k0base + kb * 32;
    const float* asrc = A + (size_t)(m0 + arow) * lda + k0 + acol;
    floatx4 av[4];
#pragma unroll
    for (int i = 0; i < 4; ++i) av[i] = *(const floatx4*)(asrc + i * 4);

    __syncthreads();
    GLD16(Zh + (size_t)zrow * ldz + k0 + zchunk,        Zs[0] + (size_t)t * 8);
    GLD16(Zh + (size_t)(zrow + 64) * ldz + k0 + zchunk, Zs[0] + (size_t)(t + 256) * 8);
    GLD16(Zm + (size_t)zrow * ldz + k0 + zchunk,        Zs[1] + (size_t)t * 8);
    GLD16(Zm + (size_t)(zrow + 64) * ldz + k0 + zchunk, Zs[1] + (size_t)(t + 256) * 8);
    GLD16(Zl + (size_t)zrow * ldz + k0 + zchunk,        Zs[2] + (size_t)t * 8);
    GLD16(Zl + (size_t)(zrow + 64) * ldz + k0 + zchunk, Zs[2] + (size_t)(t + 256) * 8);

    bf16x8 ah[2], alo[2];
    const int grow = m0 + arow;
#pragma unroll
    for (int i = 0; i < 16; ++i) {
      float v = av[i >> 2][i & 3];
      if (k0 + acol + i == grow) v = 0.0f;
      bf16 h = (bf16)v;
      ah[i >> 3][i & 7] = h;
      alo[i >> 3][i & 7] = (bf16)(v - (float)h);
    }
    const int sbase = arow * 32 + acol;
    *(bf16x8*)&Ahs[sbase] = ah[0]; *(bf16x8*)&Ahs[sbase + 8] = ah[1];
    if (aTwo) { *(bf16x8*)&Als[sbase] = alo[0]; *(bf16x8*)&Als[sbase + 8] = alo[1]; }
    __syncthreads();

    bf16x8 afh[4], afl[4], bz[3][4];
#pragma unroll
    for (int mi = 0; mi < 4; ++mi)
      afh[mi] = *(const bf16x8*)&Ahs[(wr * 64 + mi * 16 + lr) * 32 + q * 8];
#pragma unroll
    for (int s = 0; s < 3; ++s)
#pragma unroll
      for (int ni = 0; ni < 4; ++ni)
        bz[s][ni] = *(const bf16x8*)&Zs[s][(wc * 64 + ni * 16 + lr) * 32 + q * 8];
#pragma unroll
    for (int s = 0; s < 3; ++s)
#pragma unroll
      for (int mi = 0; mi < 4; ++mi)
#pragma unroll
        for (int ni = 0; ni < 4; ++ni)
          acc[mi][ni] = __builtin_amdgcn_mfma_f32_16x16x32_bf16(
              afh[mi], bz[s][ni], acc[mi][ni], 0, 0, 0);
    if (aTwo) {
#pragma unroll
      for (int mi = 0; mi < 4; ++mi)
        afl[mi] = *(const bf16x8*)&Als[(wr * 64 + mi * 16 + lr) * 32 + q * 8];
#pragma unroll
      for (int s = 0; s < 2; ++s)
#pragma unroll
        for (int mi = 0; mi < 4; ++mi)
#pragma unroll
          for (int ni = 0; ni < 4; ++ni)
            acc[mi][ni] = __builtin_amdgcn_mfma_f32_16x16x32_bf16(
                afl[mi], bz[s][ni], acc[mi][ni], 0, 0, 0);
    }
  }

#pragma unroll
  for (int mi = 0; mi < 4; ++mi)
#pragma unroll
    for (int ni = 0; ni < 4; ++ni) {
      const int col = wc * 64 + ni * 16 + lr;
      const int rowb = m0 + wr * 64 + mi * 16 + q * 4;
#pragma unroll
      for (int r = 0; r < 4; ++r)
        atomicAdd(&Y[(size_t)(rowb + r) * 128 + col], acc[mi][ni][r]);
    }
}

// ---------------------------------------------------------------------------
// Z[nr,128] = dn ⊙ (X @ W), fp32-accurate via 3-way bf16 split, 6-term MFMA.
// Emits Z fp32, Z transposed as 3 bf16 planes, zeroes Agg, block0 zeroes stats.
// ---------------------------------------------------------------------------
__global__ __launch_bounds__(256) void xw_split(
    const float* __restrict__ X,
    const bf16* __restrict__ Wh, const bf16* __restrict__ Wm, const bf16* __restrict__ Wl,
    const float* __restrict__ dnv, float* __restrict__ Z,
    bf16* __restrict__ Zht, bf16* __restrict__ Zmt, bf16* __restrict__ Zlt, int ldz,
    float* __restrict__ Agg, float* __restrict__ stats)
{
  __shared__ __align__(16) bf16 Xs[3][128 * 32];
  __shared__ __align__(16) bf16 Ws[3][128 * 32];

  const int t = threadIdx.x;
  if (blockIdx.x == 0) stats[t] = 0.0f;

  const int w = t >> 6, l = t & 63;
  const int wr = w >> 1, wc = w & 1;
  const int lr = l & 15, q = l >> 4;
  const int r0 = blockIdx.x * 128;

  const int srow = t >> 1;
  const int soff = (t & 1) * 16;
  const int sbase = srow * 32 + soff;

  floatx4 acc[4][4];
#pragma unroll
  for (int i = 0; i < 4; ++i)
#pragma unroll
    for (int j = 0; j < 4; ++j) acc[i][j] = (floatx4)0.0f;

  const bf16* wsrc[3] = {Wh, Wm, Wl};

  for (int ks = 0; ks < 4; ++ks) {
    const int k0 = ks * 32;
    float xv[16];
    const float* xsrc = X + (size_t)(r0 + srow) * 128 + k0 + soff;
#pragma unroll
    for (int i = 0; i < 16; i += 4) {
      floatx4 tmp = *(const floatx4*)(xsrc + i);
      xv[i] = tmp[0]; xv[i + 1] = tmp[1]; xv[i + 2] = tmp[2]; xv[i + 3] = tmp[3];
    }
    bf16x8 wv[3][2];
#pragma unroll
    for (int s = 0; s < 3; ++s) {
      const bf16* ws = wsrc[s] + (size_t)srow * 128 + k0 + soff;
      wv[s][0] = *(const bf16x8*)ws;
      wv[s][1] = *(const bf16x8*)(ws + 8);
    }
    bf16x8 vh[2], vm[2], vl[2];
#pragma unroll
    for (int i = 0; i < 16; ++i) {
      float v = xv[i];
      bf16 h = (bf16)v; float r1 = v - (float)h;
      bf16 m = (bf16)r1; float r2 = r1 - (float)m;
      vh[i >> 3][i & 7] = h; vm[i >> 3][i & 7] = m; vl[i >> 3][i & 7] = (bf16)r2;
    }
    __syncthreads();
    *(bf16x8*)&Xs[0][sbase] = vh[0]; *(bf16x8*)&Xs[0][sbase + 8] = vh[1];
    *(bf16x8*)&Xs[1][sbase] = vm[0]; *(bf16x8*)&Xs[1][sbase + 8] = vm[1];
    *(bf16x8*)&Xs[2][sbase] = vl[0]; *(bf16x8*)&Xs[2][sbase + 8] = vl[1];
#pragma unroll
    for (int s = 0; s < 3; ++s) {
      *(bf16x8*)&Ws[s][sbase] = wv[s][0];
      *(bf16x8*)&Ws[s][sbase + 8] = wv[s][1];
    }
    __syncthreads();

    bf16x8 af[3][4], bfg[3][4];
#pragma unroll
    for (int s = 0; s < 3; ++s) {
#pragma unroll
      for (int mi = 0; mi < 4; ++mi)
        af[s][mi] = *(const bf16x8*)&Xs[s][(wr * 64 + mi * 16 + lr) * 32 + q * 8];
#pragma unroll
      for (int ni = 0; ni < 4; ++ni)
        bfg[s][ni] = *(const bf16x8*)&Ws[s][(wc * 64 + ni * 16 + lr) * 32 + q * 8];
    }
    const int sa[6] = {0, 0, 1, 1, 0, 2};
    const int sb[6] = {0, 1, 0, 1, 2, 0};
#pragma unroll
    for (int p = 0; p < 6; ++p)
#pragma unroll
      for (int mi = 0; mi < 4; ++mi)
#pragma unroll
        for (int ni = 0; ni < 4; ++ni)
          acc[mi][ni] = __builtin_amdgcn_mfma_f32_16x16x32_bf16(
              af[sa[p]][mi], bfg[sb[p]][ni], acc[mi][ni], 0, 0, 0);
  }

#pragma unroll
  for (int mi = 0; mi < 4; ++mi) {
    const int rowb = r0 + wr * 64 + mi * 16 + q * 4;
    float dnr[4];
#pragma unroll
    for (int r = 0; r < 4; ++r) dnr[r] = dnv[rowb + r];
#pragma unroll
    for (int ni = 0; ni < 4; ++ni) {
      const int col = wc * 64 + ni * 16 + lr;
      bf16x4 h4, m4, l4;
#pragma unroll
      for (int r = 0; r < 4; ++r) {
        float v = dnr[r] * acc[mi][ni][r];
        Z[(size_t)(rowb + r) * 128 + col] = v;
        Agg[(size_t)(rowb + r) * 128 + col] = 0.0f;
        bf16 h = (bf16)v; float r1 = v - (float)h;
        bf16 m = (bf16)r1; float r2 = r1 - (float)m;
        h4[r] = h; m4[r] = m; l4[r] = (bf16)r2;
      }
      *(bf16x4*)&Zht[(size_t)col * ldz + rowb] = h4;
      *(bf16x4*)&Zmt[(size_t)col * ldz + rowb] = m4;
      *(bf16x4*)&Zlt[(size_t)col * ldz + rowb] = l4;
    }
  }
}

// ---------------------------------------------------------------------------
// small kernels
// ---------------------------------------------------------------------------
__global__ void pnorm_kernel(const float* __restrict__ pw, float* __restrict__ invp) {
  __shared__ float red[128];
  int t = threadIdx.x;
  for (int l = 0; l < 3; ++l) {
    float v = pw[l * 128 + t];
    red[t] = v * v; __syncthreads();
    for (int off = 64; off; off >>= 1) {
      if (t < off) red[t] += red[t + off];
      __syncthreads();
    }
    if (t == 0) invp[l] = 1.0f / sqrtf(red[0]);
    __syncthreads();
  }
}

// conv_w [7][k][c] fp32 -> transposed 3-way split [7][c][k] bf16
__global__ void split_w(const float* __restrict__ W, bf16* __restrict__ Wh,
                        bf16* __restrict__ Wm, bf16* __restrict__ Wl) {
  int idx = blockIdx.x * 256 + threadIdx.x;
  int l = idx >> 14, rem = idx & 16383, c = rem >> 7, k = rem & 127;
  float v = W[(l << 14) + (k << 7) + c];
  bf16 h = (bf16)v; float r1 = v - (float)h;
  bf16 m = (bf16)r1; float r2 = r1 - (float)m;
  Wh[idx] = h; Wm[idx] = m; Wl[idx] = (bf16)r2;
}

// adj fp32 -> bf16 (diag 0) + dn = rsqrt(offdiag rowsum + 2). One block/row.
__global__ void adj2bf(const float* __restrict__ adj, bf16* __restrict__ ah,
                       float* __restrict__ dn, int n) {
  int r = blockIdx.x, t = threadIdx.x;
  const float* arow = adj + (size_t)r * n;
  bf16* orow = ah + (size_t)r * n;
  float sum = 0.f;
  for (int c4 = t * 4; c4 < n; c4 += 1024) {
    floatx4 v = *(const floatx4*)(arow + c4);
    bf16x4 o;
#pragma unroll
    for (int e = 0; e < 4; ++e) {
      float x = (c4 + e == r) ? 0.0f : v[e];
      sum += x; o[e] = (bf16)x;
    }
    *(bf16x4*)&orow[c4] = o;
  }
  __shared__ float red[256];
  red[t] = sum; __syncthreads();
  for (int off = 128; off; off >>= 1) {
    if (t < off) red[t] += red[t + off];
    __syncthreads();
  }
  if (t == 0) dn[r] = 1.0f / sqrtf(red[0] + 2.0f);
}

// dn from bf16 A (diag stored 0)
__global__ void dn_rows_bf(const bf16* __restrict__ A, int lda, float* __restrict__ dn,
                           int n) {
  int r = blockIdx.x, t = threadIdx.x;
  const bf16* row = A + (size_t)r * lda;
  float sum = 0.f;
  for (int c4 = t * 4; c4 < n; c4 += 1024) {
    bf16x4 v = *(const bf16x4*)&row[c4];
#pragma unroll
    for (int e = 0; e < 4; ++e) sum += (float)v[e];
  }
  __shared__ float red[256];
  red[t] = sum; __syncthreads();
  for (int off = 128; off; off >>= 1) {
    if (t < off) red[t] += red[t + off];
    __syncthreads();
  }
  if (t == 0) dn[r] = 1.0f / sqrtf(red[0] + 2.0f);
}

// dn from fp32 A (diag stored 0)
__global__ void dn_rows(const float* __restrict__ A, int lda, float* __restrict__ dn,
                        int n) {
  int r = blockIdx.x, t = threadIdx.x;
  const float* row = A + (size_t)r * lda;
  float sum = 0.f;
  for (int c = t; c < n; c += 256)
    if (c != r) sum += row[c];
  __shared__ float red[256];
  red[t] = sum; __syncthreads();
  for (int off = 128; off; off >>= 1) {
    if (t < off) red[t] += red[t + off];
    __syncthreads();
  }
  if (t == 0) dn[r] = 1.0f / sqrtf(red[0] + 2.0f);
}

__global__ void score_kernel(const float* __restrict__ x, const float* __restrict__ p,
                             const float* __restrict__ invp, float* __restrict__ s) {
  int wave = (blockIdx.x * 256 + threadIdx.x) >> 6;
  int l = threadIdx.x & 63;
  const float* xr = x + (size_t)wave * 128;
  float partial = xr[l] * p[l] + xr[l + 64] * p[l + 64];
  for (int off = 32; off; off >>= 1) partial += __shfl_down(partial, off, 64);
  if (l == 0) s[wave] = tanhf(partial * invp[0]);
}

__global__ void kth_largest(const float* __restrict__ s, int n, int k,
                            float* __restrict__ out) {
  __shared__ float v[4096];
  int tid = threadIdx.x;
  for (int i = tid; i < n; i += 1024) v[i] = s[i];
  __syncthreads();
  for (int size2 = 2; size2 <= n; size2 <<= 1) {
    for (int stride = size2 >> 1; stride > 0; stride >>= 1) {
      for (int i = tid; i < n; i += 1024) {
        int j = i ^ stride;
        if (j > i) {
          float a = v[i], b = v[j];
          bool up = ((i & size2) == 0);
          if ((a < b) == up) { v[i] = b; v[j] = a; }
        }
      }
      __syncthreads();
    }
  }
  if (tid == 0) out[0] = v[k - 1];
}

__global__ void compact_kernel(const float* __restrict__ s, const float* __restrict__ thrp,
                               int n, int k, int* __restrict__ perm,
                               float* __restrict__ vals) {
  __shared__ int cg[1024], ce[1024];
  int tid = threadIdx.x;
  float thr = *thrp;
  int chunk = n >> 10;
  int beg = tid * chunk;
  int g = 0, e = 0;
  for (int i = 0; i < chunk; ++i) {
    float v = s[beg + i];
    g += (v > thr); e += (v == thr);
  }
  cg[tid] = g; ce[tid] = e; __syncthreads();
  for (int off = 1; off < 1024; off <<= 1) {
    int a = (tid >= off) ? cg[tid - off] : 0;
    int b = (tid >= off) ? ce[tid - off] : 0;
    __syncthreads();
    cg[tid] += a; ce[tid] += b;
    __syncthreads();
  }
  int total_gt = cg[1023];
  int pg = cg[tid] - g;
  int pe = ce[tid] - e;
  int need = k - total_gt;
  for (int i = 0; i < chunk; ++i) {
    float v = s[beg + i];
    if (v > thr) { perm[pg] = beg + i; vals[pg] = v; ++pg; }
    else if (v == thr) {
      if (pe < need) { perm[total_gt + pe] = beg + i; vals[total_gt + pe] = v; }
      ++pe;
    }
  }
}

// R[j,:] = (A + I)[perm[j], :] from bf16 source (diag substitute 1)
__global__ void gather_bf(const bf16* __restrict__ src, int lda,
                          const int* __restrict__ perm, bf16* __restrict__ R, int n) {
  int j = blockIdx.x, t = threadIdx.x;
  int r = perm[j];
  const bf16* s = src + (size_t)r * lda;
  bf16* o = R + (size_t)j * n;
  for (int c4 = t * 4; c4 < n; c4 += 1024) {
    bf16x4 v = *(const bf16x4*)&s[c4];
    if (r >= c4 && r < c4 + 4) v[r - c4] = (bf16)1.0f;
    *(bf16x4*)&o[c4] = v;
  }
}

// R[j,:] = (A + I)[perm[j], :] from fp32 source (diag substitute 1)
__global__ void gather_f32(const float* __restrict__ src, int lda,
                           const int* __restrict__ perm, bf16* __restrict__ R, int n) {
  int j = blockIdx.x, t = threadIdx.x;
  int r = perm[j];
  const float* s = src + (size_t)r * lda;
  bf16* o = R + (size_t)j * n;
  for (int c4 = t * 4; c4 < n; c4 += 1024) {
    floatx4 v = *(const floatx4*)(s + c4);
    bf16x4 ob;
#pragma unroll
    for (int e = 0; e < 4; ++e)
      ob[e] = (c4 + e == r) ? (bf16)1.0f : (bf16)v[e];
    *(bf16x4*)&o[c4] = ob;
  }
}

__global__ void pool_x(const float* __restrict__ res, const int* __restrict__ perm,
                       const float* __restrict__ vals, float* __restrict__ xp) {
  int j = blockIdx.x, c = threadIdx.x;
  xp[(size_t)j * 128 + c] = res[(size_t)perm[j] * 128 + c] * vals[j];
}

// in-place: res[perm[j],:] += up[j,:]
__global__ void scatter_add(float* __restrict__ res, const float* __restrict__ up,
                            const int* __restrict__ perm) {
  int j = blockIdx.x, c = threadIdx.x;
  int r = perm[j];
  res[(size_t)r * 128 + c] += up[(size_t)j * 128 + c];
}

// y = dn[r]*(acc + 2*Z) + bias; optional relu; store H; accumulate BN col stats
__global__ void gcn_post(const float* __restrict__ acc, const float* __restrict__ Zf,
                         const float* __restrict__ dn, const float* __restrict__ bias,
                         float* __restrict__ H, float* __restrict__ stats, int relu) {
  int c = threadIdx.x;
  int r0 = blockIdx.x * 16;
  float b = bias[c];
  float s = 0.f, qq = 0.f;
  for (int i = 0; i < 16; ++i) {
    int r = r0 + i;
    float v = dn[r] * (acc[(size_t)r * 128 + c] + 2.0f * Zf[(size_t)r * 128 + c]) + b;
    if (relu) v = fmaxf(v, 0.f);
    H[(size_t)r * 128 + c] = v;
    s += v; qq += v * v;
  }
  atomicAdd(&stats[c], s);
  atomicAdd(&stats[128 + c], qq);
}

__global__ void bn_fin(const float* __restrict__ stats, const float* __restrict__ g,
                       const float* __restrict__ b, float* __restrict__ coef, int n) {
  int c = threadIdx.x;
  float m = stats[c] / n;
  float var = stats[128 + c] / n - m * m;
  float inv = 1.0f / sqrtf(var + 1e-5f);
  float sc = g[c] * inv;
  coef[c] = sc;
  coef[128 + c] = b[c] - m * sc;
}

__global__ void bn_apply(const float* __restrict__ H, const float* __restrict__ coef,
                         float* __restrict__ xout) {
  int r = blockIdx.x, c = threadIdx.x;
  xout[(size_t)r * 128 + c] = coef[c] * H[(size_t)r * 128 + c] + coef[128 + c];
}

// ---------------------------------------------------------------------------
extern "C" void kernel_launch(void* const* d_in, const int* in_sizes, int n_in,
                              void* d_out, int out_size, void* d_ws, size_t ws_size,
                              hipStream_t stream) {
  const float* x_in   = (const float*)d_in[0];
  const float* adj    = (const float*)d_in[1];
  const float* conv_w = (const float*)d_in[2];
  const float* conv_b = (const float*)d_in[3];
  const float* pool_w = (const float*)d_in[4];
  const float* bn_g   = (const float*)d_in[5];
  const float* bn_b   = (const float*)d_in[6];
  float* out = (float*)d_out;
  (void)in_sizes; (void)n_in; (void)out_size; (void)ws_size;

  char* p = (char*)d_ws;
  auto alloc = [&](size_t bytes) -> void* {
    void* r = (void*)p;
    p += (bytes + 255) & ~(size_t)255;
    return r;
  };
  bf16*  Ah0bf = (bf16*)alloc(4096ull * 4096 * 2);
  bf16*  A1bf  = (bf16*)alloc(2048ull * 2048 * 2);
  float* A2f   = (float*)alloc(1024ull * 1024 * 4);
  float* A3f   = (float*)alloc(512ull * 512 * 4);
  bf16*  Rbuf  = (bf16*)alloc(2048ull * 4096 * 2);
  float* Cs    = (float*)alloc(136ull * 4 * 16384 * 4);   // split-K tile slices
  float* Z     = (float*)alloc(4096ull * 128 * 4);
  bf16*  Zht   = (bf16*)alloc(128ull * 4096 * 2);
  bf16*  Zmt   = (bf16*)alloc(128ull * 4096 * 2);
  bf16*  Zlt   = (bf16*)alloc(128ull * 4096 * 2);
  float* Agg   = (float*)alloc(4096ull * 128 * 4);
  float* H     = (float*)alloc(4096ull * 128 * 4);
  float* res0  = (float*)alloc(4096ull * 128 * 4);
  float* res1  = (float*)alloc(2048ull * 128 * 4);
  float* res2  = (float*)alloc(1024ull * 128 * 4);
  float* Xp    = (float*)alloc(2048ull * 128 * 4);
  float* xb0   = (float*)alloc(512ull * 128 * 4);
  float* xb1   = (float*)alloc(1024ull * 128 * 4);
  float* xb2   = (float*)alloc(2048ull * 128 * 4);
  bf16*  Wh    = (bf16*)alloc(7ull * 16384 * 2);
  bf16*  Wm    = (bf16*)alloc(7ull * 16384 * 2);
  bf16*  Wl    = (bf16*)alloc(7ull * 16384 * 2);
  float* scores = (float*)alloc(4096 * 4);
  float* thrb  = (float*)alloc(256);
  int*   perm0 = (int*)alloc(2048 * 4);
  int*   perm1 = (int*)alloc(1024 * 4);
  int*   perm2 = (int*)alloc(512 * 4);
  float* vals0 = (float*)alloc(2048 * 4);
  float* vals1 = (float*)alloc(1024 * 4);
  float* vals2 = (float*)alloc(512 * 4);
  float* dn0   = (float*)alloc(4096 * 4);
  float* dn1   = (float*)alloc(2048 * 4);
  float* dn2   = (float*)alloc(1024 * 4);
  float* dn3   = (float*)alloc(512 * 4);
  float* invp  = (float*)alloc(256);
  float* stats = (float*)alloc(1024);
  float* coef  = (float*)alloc(1024);

  // GCN layer. Abf!=null -> exact-int bf16 adjacency path; else fp32 split path.
  auto gcn = [&](int nr, const bf16* Abf, const float* Af32, const float* dnv,
                 int layer, const float* xsrc, float* xout, int relu, int aTwo) {
    xw_split<<<nr / 128, 256, 0, stream>>>(
        xsrc, Wh + layer * 16384, Wm + layer * 16384, Wl + layer * 16384, dnv,
        Z, Zht, Zmt, Zlt, nr, Agg, stats);
    if (Abf)
      agg_bf<<<dim3(nr / 128, 8), 256, 0, stream>>>(
          Abf, nr, Zht, Zmt, Zlt, nr, Agg, nr / 256);
    else
      agg_split<<<dim3(nr / 128, 8), 256, 0, stream>>>(
          Af32, nr, Zht, Zmt, Zlt, nr, Agg, nr / 256, aTwo);
    gcn_post<<<nr / 16, 128, 0, stream>>>(Agg, Z, dnv, conv_b + layer * 128, H, stats, relu);
    bn_fin<<<1, 128, 0, stream>>>(stats, bn_g + layer * 128, bn_b + layer * 128, coef, nr);
    bn_apply<<<nr, 128, 0, stream>>>(H, coef, xout);
  };

  // Pool: scores -> top-k -> symmetric augment (upper-tri, split-K slices).
  auto pool = [&](int lev, int n, const float* xprev, const bf16* srcBf,
                  const float* srcF32, bf16* outBf, float* outF32, float* dnNew,
                  int* perm, float* vals, int splitZ) {
    int k = n / 2, G = k / 128, pairs = G * (G + 1) / 2;
    score_kernel<<<n / 4, 256, 0, stream>>>(xprev, pool_w + (lev - 1) * 128,
                                            invp + (lev - 1), scores);
    kth_largest<<<1, 1024, 0, stream>>>(scores, n, k, thrb);
    compact_kernel<<<1, 1024, 0, stream>>>(scores, thrb, n, k, perm, vals);
    if (srcBf) gather_bf<<<k, 256, 0, stream>>>(srcBf, n, perm, Rbuf, n);
    else       gather_f32<<<k, 256, 0, stream>>>(srcF32, n, perm, Rbuf, n);
    gemm_sym<<<dim3(pairs, splitZ), 256, 0, stream>>>(Rbuf, Cs, n, n / (splitZ * 32), G);
    sym_post<<<pairs, 128, 0, stream>>>(Cs, outBf, outF32, k, G, pairs, splitZ);
    if (outBf) dn_rows_bf<<<k, 256, 0, stream>>>(outBf, k, dnNew, k);
    else       dn_rows<<<k, 256, 0, stream>>>(outF32, k, dnNew, k);
    pool_x<<<k, 128, 0, stream>>>(xprev, perm, vals, Xp);
  };

  // ---- prep ----
  pnorm_kernel<<<1, 128, 0, stream>>>(pool_w, invp);
  split_w<<<448, 256, 0, stream>>>(conv_w, Wh, Wm, Wl);
  adj2bf<<<4096, 256, 0, stream>>>(adj, Ah0bf, dn0, 4096);

  // ---- down ----
  gcn(4096, Ah0bf, nullptr, dn0, 0, x_in, res0, 1, 0);
  pool(1, 4096, res0, Ah0bf, nullptr, A1bf, nullptr, dn1, perm0, vals0, 4);
  gcn(2048, A1bf, nullptr, dn1, 1, Xp, res1, 1, 0);
  pool(2, 2048, res1, A1bf, nullptr, nullptr, A2f, dn2, perm1, vals1, 4);
  gcn(1024, nullptr, A2f, dn2, 2, Xp, res2, 1, 1);
  pool(3, 1024, res2, nullptr, A2f, nullptr, A3f, dn3, perm2, vals2, 8);
  gcn(512, nullptr, A3f, dn3, 3, Xp, xb0, 1, 1);

  // ---- up ---- (scatter into res_j in place; res_j not needed afterwards)
  scatter_add<<<512, 128, 0, stream>>>(res2, xb0, perm2);
  gcn(1024, nullptr, A2f, dn2, 4, res2, xb1, 1, 1);

  scatter_add<<<1024, 128, 0, stream>>>(res1, xb1, perm1);
  gcn(2048, A1bf, nullptr, dn1, 5, res1, xb2, 1, 0);

  scatter_add<<<2048, 128, 0, stream>>>(res0, xb2, perm0);
  gcn(4096, Ah0bf, nullptr, dn0, 6, res0, out, 0, 0);
}

// Round 5
// 662.018 us; speedup vs baseline: 2.0350x; 1.1231x over previous
//
#include <hip/hip_runtime.h>
#include <cstdint>
#include <cstddef>

typedef __bf16 bf16;
typedef __bf16 bf16x8 __attribute__((ext_vector_type(8)));
typedef __bf16 bf16x4 __attribute__((ext_vector_type(4)));
typedef float floatx4 __attribute__((ext_vector_type(4)));

#define GLD16(gp, lp) __builtin_amdgcn_global_load_lds( \
    (const __attribute__((address_space(1))) void*)(gp), \
    (__attribute__((address_space(3))) void*)(lp), 16, 0, 0)

// ---------------------------------------------------------------------------
// Symmetric augment GEMM: upper-tri 128x128 block pairs of C = R * R^T.
// ---------------------------------------------------------------------------
__global__ __launch_bounds__(256) void gemm_sym(
    const bf16* __restrict__ R, float* __restrict__ Cs,
    int n /*lda = K*/, int kIters, int G)
{
  __shared__ __align__(16) bf16 smem[2 * 128 * 32];
  bf16* As = smem;
  bf16* Bs = smem + 128 * 32;

  int rem = blockIdx.x, bm = 0;
  while (rem >= G - bm) { rem -= G - bm; ++bm; }
  const int bn = bm + rem;
  const int m0 = bm * 128, n0 = bn * 128;

  const int t = threadIdx.x;
  const int w = t >> 6, l = t & 63;
  const int wr = w >> 1, wc = w & 1;
  const int lr = l & 15, q = l >> 4;
  const int k0base = blockIdx.y * kIters * 32;

  const bf16* Ab = R + (size_t)m0 * n + k0base;
  const bf16* Bb = R + (size_t)n0 * n + k0base;
  const int srow = t >> 2;
  const int schunk = (t & 3) * 8;

  floatx4 acc[4][4];
#pragma unroll
  for (int i = 0; i < 4; ++i)
#pragma unroll
    for (int j = 0; j < 4; ++j) acc[i][j] = (floatx4)0.0f;

  for (int kb = 0; kb < kIters; ++kb) {
    const int k0 = kb * 32;
    __syncthreads();
    GLD16(Ab + (size_t)srow * n + k0 + schunk,        As + (size_t)t * 8);
    GLD16(Ab + (size_t)(srow + 64) * n + k0 + schunk, As + (size_t)(t + 256) * 8);
    GLD16(Bb + (size_t)srow * n + k0 + schunk,        Bs + (size_t)t * 8);
    GLD16(Bb + (size_t)(srow + 64) * n + k0 + schunk, Bs + (size_t)(t + 256) * 8);
    __syncthreads();

    bf16x8 af[4], bfr[4];
#pragma unroll
    for (int mi = 0; mi < 4; ++mi)
      af[mi] = *(const bf16x8*)&As[(wr * 64 + mi * 16 + lr) * 32 + q * 8];
#pragma unroll
    for (int ni = 0; ni < 4; ++ni)
      bfr[ni] = *(const bf16x8*)&Bs[(wc * 64 + ni * 16 + lr) * 32 + q * 8];
#pragma unroll
    for (int mi = 0; mi < 4; ++mi)
#pragma unroll
      for (int ni = 0; ni < 4; ++ni)
        acc[mi][ni] = __builtin_amdgcn_mfma_f32_16x16x32_bf16(
            af[mi], bfr[ni], acc[mi][ni], 0, 0, 0);
  }

  float* cout = Cs + ((size_t)blockIdx.y * gridDim.x + blockIdx.x) * 16384;
#pragma unroll
  for (int mi = 0; mi < 4; ++mi)
#pragma unroll
    for (int ni = 0; ni < 4; ++ni) {
      const int cl = wc * 64 + ni * 16 + lr;
      const int rb = wr * 64 + mi * 16 + q * 4;
#pragma unroll
      for (int r = 0; r < 4; ++r)
        cout[(size_t)(rb + r) * 128 + cl] = acc[mi][ni][r];
    }
}

// Sum split-K slices, write A (bf16 and/or fp32) with symmetric mirror, diag=0.
__global__ void sym_post(const float* __restrict__ Cs, bf16* __restrict__ Abf,
                         float* __restrict__ Af, int k, int G, int pairs, int nz)
{
  int rem = blockIdx.x, bm = 0;
  while (rem >= G - bm) { rem -= G - bm; ++bm; }
  const int bn = bm + rem;
  const int i = threadIdx.x;
  const int r = bm * 128 + i;
  const float* base = Cs + (size_t)blockIdx.x * 16384 + (size_t)i * 128;

  for (int jc = 0; jc < 128; jc += 16) {
    float v[16];
#pragma unroll
    for (int e = 0; e < 16; ++e) v[e] = base[jc + e];
    for (int z = 1; z < nz; ++z) {
      const float* b2 = base + (size_t)z * pairs * 16384;
#pragma unroll
      for (int e = 0; e < 16; ++e) v[e] += b2[jc + e];
    }
#pragma unroll
    for (int e = 0; e < 16; ++e) {
      const int c = bn * 128 + jc + e;
      const float val = (c == r) ? 0.0f : v[e];
      if (Abf) Abf[(size_t)r * k + c] = (bf16)val;
      if (Af)  Af[(size_t)r * k + c] = val;
      if (bm != bn) {
        if (Abf) Abf[(size_t)c * k + r] = (bf16)val;
        if (Af)  Af[(size_t)c * k + r] = val;
      }
    }
  }
}

// ---------------------------------------------------------------------------
// Aggregation (exact-int A in bf16, diag stored 0): Y += A @ Z (3 planes)
// ---------------------------------------------------------------------------
__global__ __launch_bounds__(256) void agg_bf(
    const bf16* __restrict__ A, int lda,
    const bf16* __restrict__ Zh, const bf16* __restrict__ Zm, const bf16* __restrict__ Zl,
    int ldz, float* __restrict__ Y, int kIters)
{
  __shared__ __align__(16) bf16 As[128 * 32];
  __shared__ __align__(16) bf16 Zs[3][128 * 32];

  const int t = threadIdx.x;
  const int w = t >> 6, l = t & 63;
  const int wr = w >> 1, wc = w & 1;
  const int lr = l & 15, q = l >> 4;
  const int m0 = blockIdx.x * 128;
  const int k0base = blockIdx.y * kIters * 32;

  const int srow = t >> 2;
  const int schunk = (t & 3) * 8;

  floatx4 acc[4][4];
#pragma unroll
  for (int i = 0; i < 4; ++i)
#pragma unroll
    for (int j = 0; j < 4; ++j) acc[i][j] = (floatx4)0.0f;

  for (int kb = 0; kb < kIters; ++kb) {
    const int k0 = k0base + kb * 32;
    __syncthreads();
    GLD16(A + (size_t)(m0 + srow) * lda + k0 + schunk,        As + (size_t)t * 8);
    GLD16(A + (size_t)(m0 + srow + 64) * lda + k0 + schunk,   As + (size_t)(t + 256) * 8);
    GLD16(Zh + (size_t)srow * ldz + k0 + schunk,        Zs[0] + (size_t)t * 8);
    GLD16(Zh + (size_t)(srow + 64) * ldz + k0 + schunk, Zs[0] + (size_t)(t + 256) * 8);
    GLD16(Zm + (size_t)srow * ldz + k0 + schunk,        Zs[1] + (size_t)t * 8);
    GLD16(Zm + (size_t)(srow + 64) * ldz + k0 + schunk, Zs[1] + (size_t)(t + 256) * 8);
    GLD16(Zl + (size_t)srow * ldz + k0 + schunk,        Zs[2] + (size_t)t * 8);
    GLD16(Zl + (size_t)(srow + 64) * ldz + k0 + schunk, Zs[2] + (size_t)(t + 256) * 8);
    __syncthreads();

    bf16x8 af[4], bz[3][4];
#pragma unroll
    for (int mi = 0; mi < 4; ++mi)
      af[mi] = *(const bf16x8*)&As[(wr * 64 + mi * 16 + lr) * 32 + q * 8];
#pragma unroll
    for (int s = 0; s < 3; ++s)
#pragma unroll
      for (int ni = 0; ni < 4; ++ni)
        bz[s][ni] = *(const bf16x8*)&Zs[s][(wc * 64 + ni * 16 + lr) * 32 + q * 8];
#pragma unroll
    for (int s = 0; s < 3; ++s)
#pragma unroll
      for (int mi = 0; mi < 4; ++mi)
#pragma unroll
        for (int ni = 0; ni < 4; ++ni)
          acc[mi][ni] = __builtin_amdgcn_mfma_f32_16x16x32_bf16(
              af[mi], bz[s][ni], acc[mi][ni], 0, 0, 0);
  }

#pragma unroll
  for (int mi = 0; mi < 4; ++mi)
#pragma unroll
    for (int ni = 0; ni < 4; ++ni) {
      const int col = wc * 64 + ni * 16 + lr;
      const int rowb = m0 + wr * 64 + mi * 16 + q * 4;
#pragma unroll
      for (int r = 0; r < 4; ++r)
        atomicAdd(&Y[(size_t)(rowb + r) * 128 + col], acc[mi][ni][r]);
    }
}

// ---------------------------------------------------------------------------
// Aggregation (fp32 A, on-the-fly 2-plane split, diag zeroed by index)
// ---------------------------------------------------------------------------
__global__ __launch_bounds__(256) void agg_split(
    const float* __restrict__ A, int lda,
    const bf16* __restrict__ Zh, const bf16* __restrict__ Zm, const bf16* __restrict__ Zl,
    int ldz, float* __restrict__ Y, int kIters, int aTwo)
{
  __shared__ __align__(16) bf16 Ahs[128 * 32];
  __shared__ __align__(16) bf16 Als[128 * 32];
  __shared__ __align__(16) bf16 Zs[3][128 * 32];

  const int t = threadIdx.x;
  const int w = t >> 6, l = t & 63;
  const int wr = w >> 1, wc = w & 1;
  const int lr = l & 15, q = l >> 4;
  const int m0 = blockIdx.x * 128;
  const int k0base = blockIdx.y * kIters * 32;

  const int arow = t >> 1;
  const int acol = (t & 1) * 16;
  const int zrow = t >> 2;
  const int zchunk = (t & 3) * 8;

  floatx4 acc[4][4];
#pragma unroll
  for (int i = 0; i < 4; ++i)
#pragma unroll
    for (int j = 0; j < 4; ++j) acc[i][j] = (floatx4)0.0f;

  for (int kb = 0; kb < kIters; ++kb) {
    const int k0 = k0base + kb * 32;
    const float* asrc = A + (size_t)(m0 + arow) * lda + k0 + acol;
    floatx4 av[4];
#pragma unroll
    for (int i = 0; i < 4; ++i) av[i] = *(const floatx4*)(asrc + i * 4);

    __syncthreads();
    GLD16(Zh + (size_t)zrow * ldz + k0 + zchunk,        Zs[0] + (size_t)t * 8);
    GLD16(Zh + (size_t)(zrow + 64) * ldz + k0 + zchunk, Zs[0] + (size_t)(t + 256) * 8);
    GLD16(Zm + (size_t)zrow * ldz + k0 + zchunk,        Zs[1] + (size_t)t * 8);
    GLD16(Zm + (size_t)(zrow + 64) * ldz + k0 + zchunk, Zs[1] + (size_t)(t + 256) * 8);
    GLD16(Zl + (size_t)zrow * ldz + k0 + zchunk,        Zs[2] + (size_t)t * 8);
    GLD16(Zl + (size_t)(zrow + 64) * ldz + k0 + zchunk, Zs[2] + (size_t)(t + 256) * 8);

    bf16x8 ah[2], alo[2];
    const int grow = m0 + arow;
#pragma unroll
    for (int i = 0; i < 16; ++i) {
      float v = av[i >> 2][i & 3];
      if (k0 + acol + i == grow) v = 0.0f;
      bf16 h = (bf16)v;
      ah[i >> 3][i & 7] = h;
      alo[i >> 3][i & 7] = (bf16)(v - (float)h);
    }
    const int sbase = arow * 32 + acol;
    *(bf16x8*)&Ahs[sbase] = ah[0]; *(bf16x8*)&Ahs[sbase + 8] = ah[1];
    if (aTwo) { *(bf16x8*)&Als[sbase] = alo[0]; *(bf16x8*)&Als[sbase + 8] = alo[1]; }
    __syncthreads();

    bf16x8 afh[4], afl[4], bz[3][4];
#pragma unroll
    for (int mi = 0; mi < 4; ++mi)
      afh[mi] = *(const bf16x8*)&Ahs[(wr * 64 + mi * 16 + lr) * 32 + q * 8];
#pragma unroll
    for (int s = 0; s < 3; ++s)
#pragma unroll
      for (int ni = 0; ni < 4; ++ni)
        bz[s][ni] = *(const bf16x8*)&Zs[s][(wc * 64 + ni * 16 + lr) * 32 + q * 8];
#pragma unroll
    for (int s = 0; s < 3; ++s)
#pragma unroll
      for (int mi = 0; mi < 4; ++mi)
#pragma unroll
        for (int ni = 0; ni < 4; ++ni)
          acc[mi][ni] = __builtin_amdgcn_mfma_f32_16x16x32_bf16(
              afh[mi], bz[s][ni], acc[mi][ni], 0, 0, 0);
    if (aTwo) {
#pragma unroll
      for (int mi = 0; mi < 4; ++mi)
        afl[mi] = *(const bf16x8*)&Als[(wr * 64 + mi * 16 + lr) * 32 + q * 8];
#pragma unroll
      for (int s = 0; s < 2; ++s)
#pragma unroll
        for (int mi = 0; mi < 4; ++mi)
#pragma unroll
          for (int ni = 0; ni < 4; ++ni)
            acc[mi][ni] = __builtin_amdgcn_mfma_f32_16x16x32_bf16(
                afl[mi], bz[s][ni], acc[mi][ni], 0, 0, 0);
    }
  }

#pragma unroll
  for (int mi = 0; mi < 4; ++mi)
#pragma unroll
    for (int ni = 0; ni < 4; ++ni) {
      const int col = wc * 64 + ni * 16 + lr;
      const int rowb = m0 + wr * 64 + mi * 16 + q * 4;
#pragma unroll
      for (int r = 0; r < 4; ++r)
        atomicAdd(&Y[(size_t)(rowb + r) * 128 + col], acc[mi][ni][r]);
    }
}

// ---------------------------------------------------------------------------
// Z[nr,128] = dn ⊙ ((gather?) X @ W) with optional row gather+scale (pool_x
// fused). Emits Z fp32 + 3 transposed bf16 planes; zeroes Agg; blk0 zeroes
// stats.
// ---------------------------------------------------------------------------
__global__ __launch_bounds__(256) void xw_split(
    const float* __restrict__ X, const int* __restrict__ perm,
    const float* __restrict__ vals,
    const bf16* __restrict__ Wh, const bf16* __restrict__ Wm, const bf16* __restrict__ Wl,
    const float* __restrict__ dnv, float* __restrict__ Z,
    bf16* __restrict__ Zht, bf16* __restrict__ Zmt, bf16* __restrict__ Zlt, int ldz,
    float* __restrict__ Agg, float* __restrict__ stats)
{
  __shared__ __align__(16) bf16 Xs[3][128 * 32];
  __shared__ __align__(16) bf16 Ws[3][128 * 32];

  const int t = threadIdx.x;
  if (blockIdx.x == 0) stats[t] = 0.0f;

  const int w = t >> 6, l = t & 63;
  const int wr = w >> 1, wc = w & 1;
  const int lr = l & 15, q = l >> 4;
  const int r0 = blockIdx.x * 128;

  const int srow = t >> 1;
  const int soff = (t & 1) * 16;
  const int sbase = srow * 32 + soff;

  const int row = r0 + srow;
  const int grow = perm ? perm[row] : row;
  const float scale = vals ? vals[row] : 1.0f;
  const float* xrow = X + (size_t)grow * 128;

  floatx4 acc[4][4];
#pragma unroll
  for (int i = 0; i < 4; ++i)
#pragma unroll
    for (int j = 0; j < 4; ++j) acc[i][j] = (floatx4)0.0f;

  const bf16* wsrc[3] = {Wh, Wm, Wl};

  for (int ks = 0; ks < 4; ++ks) {
    const int k0 = ks * 32;
    float xv[16];
    const float* xsrc = xrow + k0 + soff;
#pragma unroll
    for (int i = 0; i < 16; i += 4) {
      floatx4 tmp = *(const floatx4*)(xsrc + i);
      xv[i] = tmp[0] * scale; xv[i + 1] = tmp[1] * scale;
      xv[i + 2] = tmp[2] * scale; xv[i + 3] = tmp[3] * scale;
    }
    bf16x8 wv[3][2];
#pragma unroll
    for (int s = 0; s < 3; ++s) {
      const bf16* ws = wsrc[s] + (size_t)srow * 128 + k0 + soff;
      wv[s][0] = *(const bf16x8*)ws;
      wv[s][1] = *(const bf16x8*)(ws + 8);
    }
    bf16x8 vh[2], vm[2], vl[2];
#pragma unroll
    for (int i = 0; i < 16; ++i) {
      float v = xv[i];
      bf16 h = (bf16)v; float r1 = v - (float)h;
      bf16 m = (bf16)r1; float r2 = r1 - (float)m;
      vh[i >> 3][i & 7] = h; vm[i >> 3][i & 7] = m; vl[i >> 3][i & 7] = (bf16)r2;
    }
    __syncthreads();
    *(bf16x8*)&Xs[0][sbase] = vh[0]; *(bf16x8*)&Xs[0][sbase + 8] = vh[1];
    *(bf16x8*)&Xs[1][sbase] = vm[0]; *(bf16x8*)&Xs[1][sbase + 8] = vm[1];
    *(bf16x8*)&Xs[2][sbase] = vl[0]; *(bf16x8*)&Xs[2][sbase + 8] = vl[1];
#pragma unroll
    for (int s = 0; s < 3; ++s) {
      *(bf16x8*)&Ws[s][sbase] = wv[s][0];
      *(bf16x8*)&Ws[s][sbase + 8] = wv[s][1];
    }
    __syncthreads();

    bf16x8 af[3][4], bfg[3][4];
#pragma unroll
    for (int s = 0; s < 3; ++s) {
#pragma unroll
      for (int mi = 0; mi < 4; ++mi)
        af[s][mi] = *(const bf16x8*)&Xs[s][(wr * 64 + mi * 16 + lr) * 32 + q * 8];
#pragma unroll
      for (int ni = 0; ni < 4; ++ni)
        bfg[s][ni] = *(const bf16x8*)&Ws[s][(wc * 64 + ni * 16 + lr) * 32 + q * 8];
    }
    const int sa[6] = {0, 0, 1, 1, 0, 2};
    const int sb[6] = {0, 1, 0, 1, 2, 0};
#pragma unroll
    for (int p = 0; p < 6; ++p)
#pragma unroll
      for (int mi = 0; mi < 4; ++mi)
#pragma unroll
        for (int ni = 0; ni < 4; ++ni)
          acc[mi][ni] = __builtin_amdgcn_mfma_f32_16x16x32_bf16(
              af[sa[p]][mi], bfg[sb[p]][ni], acc[mi][ni], 0, 0, 0);
  }

#pragma unroll
  for (int mi = 0; mi < 4; ++mi) {
    const int rowb = r0 + wr * 64 + mi * 16 + q * 4;
    float dnr[4];
#pragma unroll
    for (int r = 0; r < 4; ++r) dnr[r] = dnv[rowb + r];
#pragma unroll
    for (int ni = 0; ni < 4; ++ni) {
      const int col = wc * 64 + ni * 16 + lr;
      bf16x4 h4, m4, l4;
#pragma unroll
      for (int r = 0; r < 4; ++r) {
        float v = dnr[r] * acc[mi][ni][r];
        Z[(size_t)(rowb + r) * 128 + col] = v;
        Agg[(size_t)(rowb + r) * 128 + col] = 0.0f;
        bf16 h = (bf16)v; float r1 = v - (float)h;
        bf16 m = (bf16)r1; float r2 = r1 - (float)m;
        h4[r] = h; m4[r] = m; l4[r] = (bf16)r2;
      }
      *(bf16x4*)&Zht[(size_t)col * ldz + rowb] = h4;
      *(bf16x4*)&Zmt[(size_t)col * ldz + rowb] = m4;
      *(bf16x4*)&Zlt[(size_t)col * ldz + rowb] = l4;
    }
  }
}

// ---------------------------------------------------------------------------
// small kernels
// ---------------------------------------------------------------------------
__global__ void pnorm_kernel(const float* __restrict__ pw, float* __restrict__ invp) {
  __shared__ float red[128];
  int t = threadIdx.x;
  for (int l = 0; l < 3; ++l) {
    float v = pw[l * 128 + t];
    red[t] = v * v; __syncthreads();
    for (int off = 64; off; off >>= 1) {
      if (t < off) red[t] += red[t + off];
      __syncthreads();
    }
    if (t == 0) invp[l] = 1.0f / sqrtf(red[0]);
    __syncthreads();
  }
}

__global__ void split_w(const float* __restrict__ W, bf16* __restrict__ Wh,
                        bf16* __restrict__ Wm, bf16* __restrict__ Wl) {
  int idx = blockIdx.x * 256 + threadIdx.x;
  int l = idx >> 14, rem = idx & 16383, c = rem >> 7, k = rem & 127;
  float v = W[(l << 14) + (k << 7) + c];
  bf16 h = (bf16)v; float r1 = v - (float)h;
  bf16 m = (bf16)r1; float r2 = r1 - (float)m;
  Wh[idx] = h; Wm[idx] = m; Wl[idx] = (bf16)r2;
}

__global__ void adj2bf(const float* __restrict__ adj, bf16* __restrict__ ah,
                       float* __restrict__ dn, int n) {
  int r = blockIdx.x, t = threadIdx.x;
  const float* arow = adj + (size_t)r * n;
  bf16* orow = ah + (size_t)r * n;
  float sum = 0.f;
  for (int c4 = t * 4; c4 < n; c4 += 1024) {
    floatx4 v = *(const floatx4*)(arow + c4);
    bf16x4 o;
#pragma unroll
    for (int e = 0; e < 4; ++e) {
      float x = (c4 + e == r) ? 0.0f : v[e];
      sum += x; o[e] = (bf16)x;
    }
    *(bf16x4*)&orow[c4] = o;
  }
  __shared__ float red[256];
  red[t] = sum; __syncthreads();
  for (int off = 128; off; off >>= 1) {
    if (t < off) red[t] += red[t + off];
    __syncthreads();
  }
  if (t == 0) dn[r] = 1.0f / sqrtf(red[0] + 2.0f);
}

__global__ void dn_rows_bf(const bf16* __restrict__ A, int lda, float* __restrict__ dn,
                           int n) {
  int r = blockIdx.x, t = threadIdx.x;
  const bf16* row = A + (size_t)r * lda;
  float sum = 0.f;
  for (int c4 = t * 4; c4 < n; c4 += 1024) {
    bf16x4 v = *(const bf16x4*)&row[c4];
#pragma unroll
    for (int e = 0; e < 4; ++e) sum += (float)v[e];
  }
  __shared__ float red[256];
  red[t] = sum; __syncthreads();
  for (int off = 128; off; off >>= 1) {
    if (t < off) red[t] += red[t + off];
    __syncthreads();
  }
  if (t == 0) dn[r] = 1.0f / sqrtf(red[0] + 2.0f);
}

__global__ void dn_rows(const float* __restrict__ A, int lda, float* __restrict__ dn,
                        int n) {
  int r = blockIdx.x, t = threadIdx.x;
  const float* row = A + (size_t)r * lda;
  float sum = 0.f;
  for (int c = t; c < n; c += 256)
    if (c != r) sum += row[c];
  __shared__ float red[256];
  red[t] = sum; __syncthreads();
  for (int off = 128; off; off >>= 1) {
    if (t < off) red[t] += red[t + off];
    __syncthreads();
  }
  if (t == 0) dn[r] = 1.0f / sqrtf(red[0] + 2.0f);
}

__global__ void score_kernel(const float* __restrict__ x, const float* __restrict__ p,
                             const float* __restrict__ invp, float* __restrict__ s) {
  int wave = (blockIdx.x * 256 + threadIdx.x) >> 6;
  int l = threadIdx.x & 63;
  const float* xr = x + (size_t)wave * 128;
  float partial = xr[l] * p[l] + xr[l + 64] * p[l + 64];
  for (int off = 32; off; off >>= 1) partial += __shfl_down(partial, off, 64);
  if (l == 0) s[wave] = tanhf(partial * invp[0]);
}

// k-th largest via 4-round 8-bit radix select on monotonic uint keys.
__device__ inline unsigned f2u(float f) {
  unsigned u = __float_as_uint(f);
  return (u & 0x80000000u) ? ~u : (u | 0x80000000u);
}
__global__ __launch_bounds__(1024) void kth_radix(
    const float* __restrict__ s, int n, int k, float* __restrict__ out)
{
  __shared__ int hist[256];
  __shared__ int suf[256];
  __shared__ unsigned sh_prefix;
  __shared__ int sh_krem;
  const int t = threadIdx.x;
  if (t == 0) { sh_prefix = 0; sh_krem = k; }

  for (int round = 0; round < 4; ++round) {
    const int shift = 24 - 8 * round;
    if (t < 256) hist[t] = 0;
    __syncthreads();
    const unsigned pref = sh_prefix;
    for (int i = t; i < n; i += 1024) {
      unsigned u = f2u(s[i]);
      if (round == 0 || (u >> (shift + 8)) == pref)
        atomicAdd(&hist[(u >> shift) & 255], 1);
    }
    __syncthreads();
    if (t < 256) suf[t] = hist[255 - t];   // suf[i] = count in bin (255-i)
    __syncthreads();
    for (int off = 1; off < 256; off <<= 1) {
      int v = (t < 256 && t >= off) ? suf[t - off] : 0;
      __syncthreads();
      if (t < 256) suf[t] += v;
      __syncthreads();
    }
    // suf[i] = count of keys with bin >= 255-i (within prefix). Find bin.
    if (t < 256) {
      int prev = (t == 0) ? 0 : suf[t - 1];
      if (suf[t] >= sh_krem && prev < sh_krem) {
        sh_prefix = (pref << 8) | (unsigned)(255 - t);
        sh_krem = sh_krem - prev;
      }
    }
    __syncthreads();
  }
  if (t == 0) {
    unsigned u = sh_prefix;
    out[0] = (u & 0x80000000u) ? __uint_as_float(u & 0x7fffffffu)
                               : __uint_as_float(~u);
  }
}

__global__ void compact_kernel(const float* __restrict__ s, const float* __restrict__ thrp,
                               int n, int k, int* __restrict__ perm,
                               float* __restrict__ vals) {
  __shared__ int cg[1024], ce[1024];
  int tid = threadIdx.x;
  float thr = *thrp;
  int chunk = n >> 10;
  int beg = tid * chunk;
  int g = 0, e = 0;
  for (int i = 0; i < chunk; ++i) {
    float v = s[beg + i];
    g += (v > thr); e += (v == thr);
  }
  cg[tid] = g; ce[tid] = e; __syncthreads();
  for (int off = 1; off < 1024; off <<= 1) {
    int a = (tid >= off) ? cg[tid - off] : 0;
    int b = (tid >= off) ? ce[tid - off] : 0;
    __syncthreads();
    cg[tid] += a; ce[tid] += b;
    __syncthreads();
  }
  int total_gt = cg[1023];
  int pg = cg[tid] - g;
  int pe = ce[tid] - e;
  int need = k - total_gt;
  for (int i = 0; i < chunk; ++i) {
    float v = s[beg + i];
    if (v > thr) { perm[pg] = beg + i; vals[pg] = v; ++pg; }
    else if (v == thr) {
      if (pe < need) { perm[total_gt + pe] = beg + i; vals[total_gt + pe] = v; }
      ++pe;
    }
  }
}

__global__ void gather_bf(const bf16* __restrict__ src, int lda,
                          const int* __restrict__ perm, bf16* __restrict__ R, int n) {
  int j = blockIdx.x, t = threadIdx.x;
  int r = perm[j];
  const bf16* s = src + (size_t)r * lda;
  bf16* o = R + (size_t)j * n;
  for (int c4 = t * 4; c4 < n; c4 += 1024) {
    bf16x4 v = *(const bf16x4*)&s[c4];
    if (r >= c4 && r < c4 + 4) v[r - c4] = (bf16)1.0f;
    *(bf16x4*)&o[c4] = v;
  }
}

__global__ void gather_f32(const float* __restrict__ src, int lda,
                           const int* __restrict__ perm, bf16* __restrict__ R, int n) {
  int j = blockIdx.x, t = threadIdx.x;
  int r = perm[j];
  const float* s = src + (size_t)r * lda;
  bf16* o = R + (size_t)j * n;
  for (int c4 = t * 4; c4 < n; c4 += 1024) {
    floatx4 v = *(const floatx4*)(s + c4);
    bf16x4 ob;
#pragma unroll
    for (int e = 0; e < 4; ++e)
      ob[e] = (c4 + e == r) ? (bf16)1.0f : (bf16)v[e];
    *(bf16x4*)&o[c4] = ob;
  }
}

__global__ void scatter_add(float* __restrict__ res, const float* __restrict__ up,
                            const int* __restrict__ perm) {
  int j = blockIdx.x, c = threadIdx.x;
  int r = perm[j];
  res[(size_t)r * 128 + c] += up[(size_t)j * 128 + c];
}

// y = dn[r]*(acc + 2*Z) + bias; optional relu; store H; accumulate BN stats
__global__ void gcn_post(const float* __restrict__ acc, const float* __restrict__ Zf,
                         const float* __restrict__ dn, const float* __restrict__ bias,
                         float* __restrict__ H, float* __restrict__ stats, int relu) {
  int c = threadIdx.x;
  int r0 = blockIdx.x * 16;
  float b = bias[c];
  float s = 0.f, qq = 0.f;
  for (int i = 0; i < 16; ++i) {
    int r = r0 + i;
    float v = dn[r] * (acc[(size_t)r * 128 + c] + 2.0f * Zf[(size_t)r * 128 + c]) + b;
    if (relu) v = fmaxf(v, 0.f);
    H[(size_t)r * 128 + c] = v;
    s += v; qq += v * v;
  }
  atomicAdd(&stats[c], s);
  atomicAdd(&stats[128 + c], qq);
}

// BN apply with per-block coef recompute (bn_fin folded in).
__global__ void bn_apply(const float* __restrict__ H, const float* __restrict__ stats,
                         const float* __restrict__ g, const float* __restrict__ b,
                         int n, float* __restrict__ xout) {
  int r = blockIdx.x, c = threadIdx.x;
  float m = stats[c] / n;
  float var = stats[128 + c] / n - m * m;
  float sc = g[c] / sqrtf(var + 1e-5f);
  float off = b[c] - m * sc;
  xout[(size_t)r * 128 + c] = sc * H[(size_t)r * 128 + c] + off;
}

// ---------------------------------------------------------------------------
extern "C" void kernel_launch(void* const* d_in, const int* in_sizes, int n_in,
                              void* d_out, int out_size, void* d_ws, size_t ws_size,
                              hipStream_t stream) {
  const float* x_in   = (const float*)d_in[0];
  const float* adj    = (const float*)d_in[1];
  const float* conv_w = (const float*)d_in[2];
  const float* conv_b = (const float*)d_in[3];
  const float* pool_w = (const float*)d_in[4];
  const float* bn_g   = (const float*)d_in[5];
  const float* bn_b   = (const float*)d_in[6];
  float* out = (float*)d_out;
  (void)in_sizes; (void)n_in; (void)out_size; (void)ws_size;

  char* p = (char*)d_ws;
  auto alloc = [&](size_t bytes) -> void* {
    void* r = (void*)p;
    p += (bytes + 255) & ~(size_t)255;
    return r;
  };
  bf16*  Ah0bf = (bf16*)alloc(4096ull * 4096 * 2);
  bf16*  A1bf  = (bf16*)alloc(2048ull * 2048 * 2);
  float* A2f   = (float*)alloc(1024ull * 1024 * 4);
  float* A3f   = (float*)alloc(512ull * 512 * 4);
  bf16*  Rbuf  = (bf16*)alloc(2048ull * 4096 * 2);
  float* Cs    = (float*)alloc(136ull * 4 * 16384 * 4);
  float* Z     = (float*)alloc(4096ull * 128 * 4);
  bf16*  Zht   = (bf16*)alloc(128ull * 4096 * 2);
  bf16*  Zmt   = (bf16*)alloc(128ull * 4096 * 2);
  bf16*  Zlt   = (bf16*)alloc(128ull * 4096 * 2);
  float* Agg   = (float*)alloc(4096ull * 128 * 4);
  float* H     = (float*)alloc(4096ull * 128 * 4);
  float* res0  = (float*)alloc(4096ull * 128 * 4);
  float* res1  = (float*)alloc(2048ull * 128 * 4);
  float* res2  = (float*)alloc(1024ull * 128 * 4);
  float* xb0   = (float*)alloc(512ull * 128 * 4);
  float* xb1   = (float*)alloc(1024ull * 128 * 4);
  float* xb2   = (float*)alloc(2048ull * 128 * 4);
  bf16*  Wh    = (bf16*)alloc(7ull * 16384 * 2);
  bf16*  Wm    = (bf16*)alloc(7ull * 16384 * 2);
  bf16*  Wl    = (bf16*)alloc(7ull * 16384 * 2);
  float* scores = (float*)alloc(4096 * 4);
  float* thrb  = (float*)alloc(256);
  int*   perm0 = (int*)alloc(2048 * 4);
  int*   perm1 = (int*)alloc(1024 * 4);
  int*   perm2 = (int*)alloc(512 * 4);
  float* vals0 = (float*)alloc(2048 * 4);
  float* vals1 = (float*)alloc(1024 * 4);
  float* vals2 = (float*)alloc(512 * 4);
  float* dn0   = (float*)alloc(4096 * 4);
  float* dn1   = (float*)alloc(2048 * 4);
  float* dn2   = (float*)alloc(1024 * 4);
  float* dn3   = (float*)alloc(512 * 4);
  float* invp  = (float*)alloc(256);
  float* stats = (float*)alloc(1024);

  // GCN layer; optional (perm, vals) fuses the top-k pooling gather.
  auto gcn = [&](int nr, const bf16* Abf, const float* Af32, const float* dnv,
                 int layer, const float* xsrc, const int* perm, const float* vals,
                 float* xout, int relu, int aTwo) {
    xw_split<<<nr / 128, 256, 0, stream>>>(
        xsrc, perm, vals,
        Wh + layer * 16384, Wm + layer * 16384, Wl + layer * 16384, dnv,
        Z, Zht, Zmt, Zlt, nr, Agg, stats);
    if (Abf)
      agg_bf<<<dim3(nr / 128, 8), 256, 0, stream>>>(
          Abf, nr, Zht, Zmt, Zlt, nr, Agg, nr / 256);
    else
      agg_split<<<dim3(nr / 128, 8), 256, 0, stream>>>(
          Af32, nr, Zht, Zmt, Zlt, nr, Agg, nr / 256, aTwo);
    gcn_post<<<nr / 16, 128, 0, stream>>>(Agg, Z, dnv, conv_b + layer * 128, H, stats, relu);
    bn_apply<<<nr, 128, 0, stream>>>(H, stats, bn_g + layer * 128, bn_b + layer * 128,
                                     nr, xout);
  };

  auto pool = [&](int lev, int n, const float* xprev, const bf16* srcBf,
                  const float* srcF32, bf16* outBf, float* outF32, float* dnNew,
                  int* perm, float* vals, int splitZ) {
    int k = n / 2, G = k / 128, pairs = G * (G + 1) / 2;
    score_kernel<<<n / 4, 256, 0, stream>>>(xprev, pool_w + (lev - 1) * 128,
                                            invp + (lev - 1), scores);
    kth_radix<<<1, 1024, 0, stream>>>(scores, n, k, thrb);
    compact_kernel<<<1, 1024, 0, stream>>>(scores, thrb, n, k, perm, vals);
    if (srcBf) gather_bf<<<k, 256, 0, stream>>>(srcBf, n, perm, Rbuf, n);
    else       gather_f32<<<k, 256, 0, stream>>>(srcF32, n, perm, Rbuf, n);
    gemm_sym<<<dim3(pairs, splitZ), 256, 0, stream>>>(Rbuf, Cs, n, n / (splitZ * 32), G);
    sym_post<<<pairs, 128, 0, stream>>>(Cs, outBf, outF32, k, G, pairs, splitZ);
    if (outBf) dn_rows_bf<<<k, 256, 0, stream>>>(outBf, k, dnNew, k);
    else       dn_rows<<<k, 256, 0, stream>>>(outF32, k, dnNew, k);
  };

  // ---- prep ----
  pnorm_kernel<<<1, 128, 0, stream>>>(pool_w, invp);
  split_w<<<448, 256, 0, stream>>>(conv_w, Wh, Wm, Wl);
  adj2bf<<<4096, 256, 0, stream>>>(adj, Ah0bf, dn0, 4096);

  // ---- down ----
  gcn(4096, Ah0bf, nullptr, dn0, 0, x_in, nullptr, nullptr, res0, 1, 0);
  pool(1, 4096, res0, Ah0bf, nullptr, A1bf, nullptr, dn1, perm0, vals0, 4);
  gcn(2048, A1bf, nullptr, dn1, 1, res0, perm0, vals0, res1, 1, 0);
  pool(2, 2048, res1, A1bf, nullptr, nullptr, A2f, dn2, perm1, vals1, 4);
  gcn(1024, nullptr, A2f, dn2, 2, res1, perm1, vals1, res2, 1, 1);
  pool(3, 1024, res2, nullptr, A2f, nullptr, A3f, dn3, perm2, vals2, 8);
  gcn(512, nullptr, A3f, dn3, 3, res2, perm2, vals2, xb0, 1, 1);

  // ---- up ----
  scatter_add<<<512, 128, 0, stream>>>(res2, xb0, perm2);
  gcn(1024, nullptr, A2f, dn2, 4, res2, nullptr, nullptr, xb1, 1, 1);

  scatter_add<<<1024, 128, 0, stream>>>(res1, xb1, perm1);
  gcn(2048, A1bf, nullptr, dn1, 5, res1, nullptr, nullptr, xb2, 1, 0);

  scatter_add<<<2048, 128, 0, stream>>>(res0, xb2, perm0);
  gcn(4096, Ah0bf, nullptr, dn0, 6, res0, nullptr, nullptr, out, 0, 0);
}

// Round 8
// 658.450 us; speedup vs baseline: 2.0461x; 1.0054x over previous
//
#include <hip/hip_runtime.h>
#include <cstdint>
#include <cstddef>

typedef __bf16 bf16;
typedef __bf16 bf16x8 __attribute__((ext_vector_type(8)));
typedef __bf16 bf16x4 __attribute__((ext_vector_type(4)));
typedef float floatx4 __attribute__((ext_vector_type(4)));

#define GLD16(gp, lp) __builtin_amdgcn_global_load_lds( \
    (const __attribute__((address_space(1))) void*)(gp), \
    (__attribute__((address_space(3))) void*)(lp), 16, 0, 0)

// ---------------------------------------------------------------------------
// Symmetric augment GEMM (round-5 form): upper-tri 128x128 block pairs of
// C = R * R^T, R [k x n] bf16 (gathered rows of A+I). fp32 slices, no atomics.
// ---------------------------------------------------------------------------
__global__ __launch_bounds__(256) void gemm_sym(
    const bf16* __restrict__ R, float* __restrict__ Cs,
    int n /*lda = K*/, int kIters, int G)
{
  __shared__ __align__(16) bf16 smem[2 * 128 * 32];
  bf16* As = smem;
  bf16* Bs = smem + 128 * 32;

  int rem = blockIdx.x, bm = 0;
  while (rem >= G - bm) { rem -= G - bm; ++bm; }
  const int bn = bm + rem;
  const int m0 = bm * 128, n0 = bn * 128;

  const int t = threadIdx.x;
  const int w = t >> 6, l = t & 63;
  const int wr = w >> 1, wc = w & 1;
  const int lr = l & 15, q = l >> 4;
  const int k0base = blockIdx.y * kIters * 32;

  const bf16* Ab = R + (size_t)m0 * n + k0base;
  const bf16* Bb = R + (size_t)n0 * n + k0base;
  const int srow = t >> 2;
  const int schunk = (t & 3) * 8;

  floatx4 acc[4][4];
#pragma unroll
  for (int i = 0; i < 4; ++i)
#pragma unroll
    for (int j = 0; j < 4; ++j) acc[i][j] = (floatx4)0.0f;

  for (int kb = 0; kb < kIters; ++kb) {
    const int k0 = kb * 32;
    __syncthreads();
    GLD16(Ab + (size_t)srow * n + k0 + schunk,        As + (size_t)t * 8);
    GLD16(Ab + (size_t)(srow + 64) * n + k0 + schunk, As + (size_t)(t + 256) * 8);
    GLD16(Bb + (size_t)srow * n + k0 + schunk,        Bs + (size_t)t * 8);
    GLD16(Bb + (size_t)(srow + 64) * n + k0 + schunk, Bs + (size_t)(t + 256) * 8);
    __syncthreads();

    bf16x8 af[4], bfr[4];
#pragma unroll
    for (int mi = 0; mi < 4; ++mi)
      af[mi] = *(const bf16x8*)&As[(wr * 64 + mi * 16 + lr) * 32 + q * 8];
#pragma unroll
    for (int ni = 0; ni < 4; ++ni)
      bfr[ni] = *(const bf16x8*)&Bs[(wc * 64 + ni * 16 + lr) * 32 + q * 8];
#pragma unroll
    for (int mi = 0; mi < 4; ++mi)
#pragma unroll
      for (int ni = 0; ni < 4; ++ni)
        acc[mi][ni] = __builtin_amdgcn_mfma_f32_16x16x32_bf16(
            af[mi], bfr[ni], acc[mi][ni], 0, 0, 0);
  }

  float* cout = Cs + ((size_t)blockIdx.y * gridDim.x + blockIdx.x) * 16384;
#pragma unroll
  for (int mi = 0; mi < 4; ++mi)
#pragma unroll
    for (int ni = 0; ni < 4; ++ni) {
      const int cl = wc * 64 + ni * 16 + lr;
      const int rb = wr * 64 + mi * 16 + q * 4;
#pragma unroll
      for (int r = 0; r < 4; ++r)
        cout[(size_t)(rb + r) * 128 + cl] = acc[mi][ni][r];
    }
}

// Sum split-K slices, write A (bf16 and/or fp32) with symmetric mirror, diag=0.
__global__ void sym_post(const float* __restrict__ Cs, bf16* __restrict__ Abf,
                         float* __restrict__ Af, int k, int G, int pairs, int nz)
{
  int rem = blockIdx.x, bm = 0;
  while (rem >= G - bm) { rem -= G - bm; ++bm; }
  const int bn = bm + rem;
  const int i = threadIdx.x;
  const int r = bm * 128 + i;
  const float* base = Cs + (size_t)blockIdx.x * 16384 + (size_t)i * 128;

  for (int jc = 0; jc < 128; jc += 16) {
    float v[16];
#pragma unroll
    for (int e = 0; e < 16; ++e) v[e] = base[jc + e];
    for (int z = 1; z < nz; ++z) {
      const float* b2 = base + (size_t)z * pairs * 16384;
#pragma unroll
      for (int e = 0; e < 16; ++e) v[e] += b2[jc + e];
    }
#pragma unroll
    for (int e = 0; e < 16; ++e) {
      const int c = bn * 128 + jc + e;
      const float val = (c == r) ? 0.0f : v[e];
      if (Abf) Abf[(size_t)r * k + c] = (bf16)val;
      if (Af)  Af[(size_t)r * k + c] = val;
      if (bm != bn) {
        if (Abf) Abf[(size_t)c * k + r] = (bf16)val;
        if (Af)  Af[(size_t)c * k + r] = val;
      }
    }
  }
}

// ---------------------------------------------------------------------------
// Aggregation (exact-int A in bf16, diag stored 0): Y += A @ Z (3 planes)
// ---------------------------------------------------------------------------
__global__ __launch_bounds__(256) void agg_bf(
    const bf16* __restrict__ A, int lda,
    const bf16* __restrict__ Zh, const bf16* __restrict__ Zm, const bf16* __restrict__ Zl,
    int ldz, float* __restrict__ Y, int kIters)
{
  __shared__ __align__(16) bf16 As[128 * 32];
  __shared__ __align__(16) bf16 Zs[3][128 * 32];

  const int t = threadIdx.x;
  const int w = t >> 6, l = t & 63;
  const int wr = w >> 1, wc = w & 1;
  const int lr = l & 15, q = l >> 4;
  const int m0 = blockIdx.x * 128;
  const int k0base = blockIdx.y * kIters * 32;

  const int srow = t >> 2;
  const int schunk = (t & 3) * 8;

  floatx4 acc[4][4];
#pragma unroll
  for (int i = 0; i < 4; ++i)
#pragma unroll
    for (int j = 0; j < 4; ++j) acc[i][j] = (floatx4)0.0f;

  for (int kb = 0; kb < kIters; ++kb) {
    const int k0 = k0base + kb * 32;
    __syncthreads();
    GLD16(A + (size_t)(m0 + srow) * lda + k0 + schunk,        As + (size_t)t * 8);
    GLD16(A + (size_t)(m0 + srow + 64) * lda + k0 + schunk,   As + (size_t)(t + 256) * 8);
    GLD16(Zh + (size_t)srow * ldz + k0 + schunk,        Zs[0] + (size_t)t * 8);
    GLD16(Zh + (size_t)(srow + 64) * ldz + k0 + schunk, Zs[0] + (size_t)(t + 256) * 8);
    GLD16(Zm + (size_t)srow * ldz + k0 + schunk,        Zs[1] + (size_t)t * 8);
    GLD16(Zm + (size_t)(srow + 64) * ldz + k0 + schunk, Zs[1] + (size_t)(t + 256) * 8);
    GLD16(Zl + (size_t)srow * ldz + k0 + schunk,        Zs[2] + (size_t)t * 8);
    GLD16(Zl + (size_t)(srow + 64) * ldz + k0 + schunk, Zs[2] + (size_t)(t + 256) * 8);
    __syncthreads();

    bf16x8 af[4], bz[3][4];
#pragma unroll
    for (int mi = 0; mi < 4; ++mi)
      af[mi] = *(const bf16x8*)&As[(wr * 64 + mi * 16 + lr) * 32 + q * 8];
#pragma unroll
    for (int s = 0; s < 3; ++s)
#pragma unroll
      for (int ni = 0; ni < 4; ++ni)
        bz[s][ni] = *(const bf16x8*)&Zs[s][(wc * 64 + ni * 16 + lr) * 32 + q * 8];
#pragma unroll
    for (int s = 0; s < 3; ++s)
#pragma unroll
      for (int mi = 0; mi < 4; ++mi)
#pragma unroll
        for (int ni = 0; ni < 4; ++ni)
          acc[mi][ni] = __builtin_amdgcn_mfma_f32_16x16x32_bf16(
              af[mi], bz[s][ni], acc[mi][ni], 0, 0, 0);
  }

#pragma unroll
  for (int mi = 0; mi < 4; ++mi)
#pragma unroll
    for (int ni = 0; ni < 4; ++ni) {
      const int col = wc * 64 + ni * 16 + lr;
      const int rowb = m0 + wr * 64 + mi * 16 + q * 4;
#pragma unroll
      for (int r = 0; r < 4; ++r)
        atomicAdd(&Y[(size_t)(rowb + r) * 128 + col], acc[mi][ni][r]);
    }
}

// ---------------------------------------------------------------------------
// Aggregation (fp32 A, on-the-fly 2-plane split, diag zeroed by index)
// ---------------------------------------------------------------------------
__global__ __launch_bounds__(256) void agg_split(
    const float* __restrict__ A, int lda,
    const bf16* __restrict__ Zh, const bf16* __restrict__ Zm, const bf16* __restrict__ Zl,
    int ldz, float* __restrict__ Y, int kIters, int aTwo)
{
  __shared__ __align__(16) bf16 Ahs[128 * 32];
  __shared__ __align__(16) bf16 Als[128 * 32];
  __shared__ __align__(16) bf16 Zs[3][128 * 32];

  const int t = threadIdx.x;
  const int w = t >> 6, l = t & 63;
  const int wr = w >> 1, wc = w & 1;
  const int lr = l & 15, q = l >> 4;
  const int m0 = blockIdx.x * 128;
  const int k0base = blockIdx.y * kIters * 32;

  const int arow = t >> 1;
  const int acol = (t & 1) * 16;
  const int zrow = t >> 2;
  const int zchunk = (t & 3) * 8;

  floatx4 acc[4][4];
#pragma unroll
  for (int i = 0; i < 4; ++i)
#pragma unroll
    for (int j = 0; j < 4; ++j) acc[i][j] = (floatx4)0.0f;

  for (int kb = 0; kb < kIters; ++kb) {
    const int k0 = k0base + kb * 32;
    const float* asrc = A + (size_t)(m0 + arow) * lda + k0 + acol;
    floatx4 av[4];
#pragma unroll
    for (int i = 0; i < 4; ++i) av[i] = *(const floatx4*)(asrc + i * 4);

    __syncthreads();
    GLD16(Zh + (size_t)zrow * ldz + k0 + zchunk,        Zs[0] + (size_t)t * 8);
    GLD16(Zh + (size_t)(zrow + 64) * ldz + k0 + zchunk, Zs[0] + (size_t)(t + 256) * 8);
    GLD16(Zm + (size_t)zrow * ldz + k0 + zchunk,        Zs[1] + (size_t)t * 8);
    GLD16(Zm + (size_t)(zrow + 64) * ldz + k0 + zchunk, Zs[1] + (size_t)(t + 256) * 8);
    GLD16(Zl + (size_t)zrow * ldz + k0 + zchunk,        Zs[2] + (size_t)t * 8);
    GLD16(Zl + (size_t)(zrow + 64) * ldz + k0 + zchunk, Zs[2] + (size_t)(t + 256) * 8);

    bf16x8 ah[2], alo[2];
    const int grow = m0 + arow;
#pragma unroll
    for (int i = 0; i < 16; ++i) {
      float v = av[i >> 2][i & 3];
      if (k0 + acol + i == grow) v = 0.0f;
      bf16 h = (bf16)v;
      ah[i >> 3][i & 7] = h;
      alo[i >> 3][i & 7] = (bf16)(v - (float)h);
    }
    const int sbase = arow * 32 + acol;
    *(bf16x8*)&Ahs[sbase] = ah[0]; *(bf16x8*)&Ahs[sbase + 8] = ah[1];
    if (aTwo) { *(bf16x8*)&Als[sbase] = alo[0]; *(bf16x8*)&Als[sbase + 8] = alo[1]; }
    __syncthreads();

    bf16x8 afh[4], afl[4], bz[3][4];
#pragma unroll
    for (int mi = 0; mi < 4; ++mi)
      afh[mi] = *(const bf16x8*)&Ahs[(wr * 64 + mi * 16 + lr) * 32 + q * 8];
#pragma unroll
    for (int s = 0; s < 3; ++s)
#pragma unroll
      for (int ni = 0; ni < 4; ++ni)
        bz[s][ni] = *(const bf16x8*)&Zs[s][(wc * 64 + ni * 16 + lr) * 32 + q * 8];
#pragma unroll
    for (int s = 0; s < 3; ++s)
#pragma unroll
      for (int mi = 0; mi < 4; ++mi)
#pragma unroll
        for (int ni = 0; ni < 4; ++ni)
          acc[mi][ni] = __builtin_amdgcn_mfma_f32_16x16x32_bf16(
              afh[mi], bz[s][ni], acc[mi][ni], 0, 0, 0);
    if (aTwo) {
#pragma unroll
      for (int mi = 0; mi < 4; ++mi)
        afl[mi] = *(const bf16x8*)&Als[(wr * 64 + mi * 16 + lr) * 32 + q * 8];
#pragma unroll
      for (int s = 0; s < 2; ++s)
#pragma unroll
        for (int mi = 0; mi < 4; ++mi)
#pragma unroll
          for (int ni = 0; ni < 4; ++ni)
            acc[mi][ni] = __builtin_amdgcn_mfma_f32_16x16x32_bf16(
                afl[mi], bz[s][ni], acc[mi][ni], 0, 0, 0);
    }
  }

#pragma unroll
  for (int mi = 0; mi < 4; ++mi)
#pragma unroll
    for (int ni = 0; ni < 4; ++ni) {
      const int col = wc * 64 + ni * 16 + lr;
      const int rowb = m0 + wr * 64 + mi * 16 + q * 4;
#pragma unroll
      for (int r = 0; r < 4; ++r)
        atomicAdd(&Y[(size_t)(rowb + r) * 128 + col], acc[mi][ni][r]);
    }
}

// ---------------------------------------------------------------------------
// Z[nr,128] = dn ⊙ (x @ W); x row = X[perm[row]]*vals[row]  (pool fusion)
//                       or  X[row] + up[inv[row]]            (unpool fusion)
// Emits Z fp32 + 3 transposed bf16 planes; zeroes Agg; blk0 zeroes stats.
// ---------------------------------------------------------------------------
__global__ __launch_bounds__(256) void xw_split(
    const float* __restrict__ X, const int* __restrict__ perm,
    const float* __restrict__ vals,
    const float* __restrict__ up, const int* __restrict__ inv,
    const bf16* __restrict__ Wh, const bf16* __restrict__ Wm, const bf16* __restrict__ Wl,
    const float* __restrict__ dnv, float* __restrict__ Z,
    bf16* __restrict__ Zht, bf16* __restrict__ Zmt, bf16* __restrict__ Zlt, int ldz,
    float* __restrict__ Agg, float* __restrict__ stats)
{
  __shared__ __align__(16) bf16 Xs[3][128 * 32];
  __shared__ __align__(16) bf16 Ws[3][128 * 32];

  const int t = threadIdx.x;
  if (blockIdx.x == 0) stats[t] = 0.0f;

  const int w = t >> 6, l = t & 63;
  const int wr = w >> 1, wc = w & 1;
  const int lr = l & 15, q = l >> 4;
  const int r0 = blockIdx.x * 128;

  const int srow = t >> 1;
  const int soff = (t & 1) * 16;
  const int sbase = srow * 32 + soff;

  const int row = r0 + srow;
  int grow = row;
  float scale = 1.0f;
  if (perm) { grow = perm[row]; scale = vals[row]; }
  const float* xrow = X + (size_t)grow * 128;
  const float* uprow = nullptr;
  if (up) { int j = inv[row]; if (j >= 0) uprow = up + (size_t)j * 128; }

  floatx4 acc[4][4];
#pragma unroll
  for (int i = 0; i < 4; ++i)
#pragma unroll
    for (int j = 0; j < 4; ++j) acc[i][j] = (floatx4)0.0f;

  const bf16* wsrc[3] = {Wh, Wm, Wl};

  for (int ks = 0; ks < 4; ++ks) {
    const int k0 = ks * 32;
    float xv[16];
#pragma unroll
    for (int i = 0; i < 16; i += 4) {
      floatx4 tmp = *(const floatx4*)(xrow + k0 + soff + i);
      if (uprow) {
        floatx4 u = *(const floatx4*)(uprow + k0 + soff + i);
        tmp += u;
      }
      xv[i] = tmp[0] * scale; xv[i + 1] = tmp[1] * scale;
      xv[i + 2] = tmp[2] * scale; xv[i + 3] = tmp[3] * scale;
    }
    bf16x8 wv[3][2];
#pragma unroll
    for (int s = 0; s < 3; ++s) {
      const bf16* ws = wsrc[s] + (size_t)srow * 128 + k0 + soff;
      wv[s][0] = *(const bf16x8*)ws;
      wv[s][1] = *(const bf16x8*)(ws + 8);
    }
    bf16x8 vh[2], vm[2], vl[2];
#pragma unroll
    for (int i = 0; i < 16; ++i) {
      float v = xv[i];
      bf16 h = (bf16)v; float r1 = v - (float)h;
      bf16 m = (bf16)r1; float r2 = r1 - (float)m;
      vh[i >> 3][i & 7] = h; vm[i >> 3][i & 7] = m; vl[i >> 3][i & 7] = (bf16)r2;
    }
    __syncthreads();
    *(bf16x8*)&Xs[0][sbase] = vh[0]; *(bf16x8*)&Xs[0][sbase + 8] = vh[1];
    *(bf16x8*)&Xs[1][sbase] = vm[0]; *(bf16x8*)&Xs[1][sbase + 8] = vm[1];
    *(bf16x8*)&Xs[2][sbase] = vl[0]; *(bf16x8*)&Xs[2][sbase + 8] = vl[1];
#pragma unroll
    for (int s = 0; s < 3; ++s) {
      *(bf16x8*)&Ws[s][sbase] = wv[s][0];
      *(bf16x8*)&Ws[s][sbase + 8] = wv[s][1];
    }
    __syncthreads();

    bf16x8 af[3][4], bfg[3][4];
#pragma unroll
    for (int s = 0; s < 3; ++s) {
#pragma unroll
      for (int mi = 0; mi < 4; ++mi)
        af[s][mi] = *(const bf16x8*)&Xs[s][(wr * 64 + mi * 16 + lr) * 32 + q * 8];
#pragma unroll
      for (int ni = 0; ni < 4; ++ni)
        bfg[s][ni] = *(const bf16x8*)&Ws[s][(wc * 64 + ni * 16 + lr) * 32 + q * 8];
    }
    const int sa[6] = {0, 0, 1, 1, 0, 2};
    const int sb[6] = {0, 1, 0, 1, 2, 0};
#pragma unroll
    for (int p = 0; p < 6; ++p)
#pragma unroll
      for (int mi = 0; mi < 4; ++mi)
#pragma unroll
        for (int ni = 0; ni < 4; ++ni)
          acc[mi][ni] = __builtin_amdgcn_mfma_f32_16x16x32_bf16(
              af[sa[p]][mi], bfg[sb[p]][ni], acc[mi][ni], 0, 0, 0);
  }

#pragma unroll
  for (int mi = 0; mi < 4; ++mi) {
    const int rowb = r0 + wr * 64 + mi * 16 + q * 4;
    float dnr[4];
#pragma unroll
    for (int r = 0; r < 4; ++r) dnr[r] = dnv[rowb + r];
#pragma unroll
    for (int ni = 0; ni < 4; ++ni) {
      const int col = wc * 64 + ni * 16 + lr;
      bf16x4 h4, m4, l4;
#pragma unroll
      for (int r = 0; r < 4; ++r) {
        float v = dnr[r] * acc[mi][ni][r];
        Z[(size_t)(rowb + r) * 128 + col] = v;
        Agg[(size_t)(rowb + r) * 128 + col] = 0.0f;
        bf16 h = (bf16)v; float r1 = v - (float)h;
        bf16 m = (bf16)r1; float r2 = r1 - (float)m;
        h4[r] = h; m4[r] = m; l4[r] = (bf16)r2;
      }
      *(bf16x4*)&Zht[(size_t)col * ldz + rowb] = h4;
      *(bf16x4*)&Zmt[(size_t)col * ldz + rowb] = m4;
      *(bf16x4*)&Zlt[(size_t)col * ldz + rowb] = l4;
    }
  }
}

// ---------------------------------------------------------------------------
// small kernels
// ---------------------------------------------------------------------------
__global__ void pnorm_kernel(const float* __restrict__ pw, float* __restrict__ invp) {
  __shared__ float red[128];
  int t = threadIdx.x;
  for (int l = 0; l < 3; ++l) {
    float v = pw[l * 128 + t];
    red[t] = v * v; __syncthreads();
    for (int off = 64; off; off >>= 1) {
      if (t < off) red[t] += red[t + off];
      __syncthreads();
    }
    if (t == 0) invp[l] = 1.0f / sqrtf(red[0]);
    __syncthreads();
  }
}

__global__ void split_w(const float* __restrict__ W, bf16* __restrict__ Wh,
                        bf16* __restrict__ Wm, bf16* __restrict__ Wl) {
  int idx = blockIdx.x * 256 + threadIdx.x;
  int l = idx >> 14, rem = idx & 16383, c = rem >> 7, k = rem & 127;
  float v = W[(l << 14) + (k << 7) + c];
  bf16 h = (bf16)v; float r1 = v - (float)h;
  bf16 m = (bf16)r1; float r2 = r1 - (float)m;
  Wh[idx] = h; Wm[idx] = m; Wl[idx] = (bf16)r2;
}

__global__ void adj2bf(const float* __restrict__ adj, bf16* __restrict__ ah,
                       float* __restrict__ dn, int n) {
  int r = blockIdx.x, t = threadIdx.x;
  const float* arow = adj + (size_t)r * n;
  bf16* orow = ah + (size_t)r * n;
  float sum = 0.f;
  for (int c4 = t * 4; c4 < n; c4 += 1024) {
    floatx4 v = *(const floatx4*)(arow + c4);
    bf16x4 o;
#pragma unroll
    for (int e = 0; e < 4; ++e) {
      float x = (c4 + e == r) ? 0.0f : v[e];
      sum += x; o[e] = (bf16)x;
    }
    *(bf16x4*)&orow[c4] = o;
  }
  __shared__ float red[256];
  red[t] = sum; __syncthreads();
  for (int off = 128; off; off >>= 1) {
    if (t < off) red[t] += red[t + off];
    __syncthreads();
  }
  if (t == 0) dn[r] = 1.0f / sqrtf(red[0] + 2.0f);
}

__global__ void dn_rows_bf(const bf16* __restrict__ A, int lda, float* __restrict__ dn,
                           int n) {
  int r = blockIdx.x, t = threadIdx.x;
  const bf16* row = A + (size_t)r * lda;
  float sum = 0.f;
  for (int c4 = t * 4; c4 < n; c4 += 1024) {
    bf16x4 v = *(const bf16x4*)&row[c4];
#pragma unroll
    for (int e = 0; e < 4; ++e) sum += (float)v[e];
  }
  __shared__ float red[256];
  red[t] = sum; __syncthreads();
  for (int off = 128; off; off >>= 1) {
    if (t < off) red[t] += red[t + off];
    __syncthreads();
  }
  if (t == 0) dn[r] = 1.0f / sqrtf(red[0] + 2.0f);
}

__global__ void dn_rows(const float* __restrict__ A, int lda, float* __restrict__ dn,
                        int n) {
  int r = blockIdx.x, t = threadIdx.x;
  const float* row = A + (size_t)r * lda;
  float sum = 0.f;
  for (int c = t; c < n; c += 256)
    if (c != r) sum += row[c];
  __shared__ float red[256];
  red[t] = sum; __syncthreads();
  for (int off = 128; off; off >>= 1) {
    if (t < off) red[t] += red[t + off];
    __syncthreads();
  }
  if (t == 0) dn[r] = 1.0f / sqrtf(red[0] + 2.0f);
}

// k-th largest via 4-round 8-bit radix select (snapshot-fixed select step).
__device__ inline unsigned f2u(float f) {
  unsigned u = __float_as_uint(f);
  return (u & 0x80000000u) ? ~u : (u | 0x80000000u);
}
__global__ __launch_bounds__(1024) void kth_radix(
    const float* __restrict__ s, int n, int k, float* __restrict__ out)
{
  __shared__ int hist[256];
  __shared__ int suf[256];
  __shared__ unsigned sh_prefix;
  __shared__ int sh_krem;
  const int t = threadIdx.x;
  if (t == 0) { sh_prefix = 0; sh_krem = k; }

  for (int round = 0; round < 4; ++round) {
    const int shift = 24 - 8 * round;
    if (t < 256) hist[t] = 0;
    __syncthreads();
    const unsigned pref = sh_prefix;   // snapshot after barrier
    const int krem = sh_krem;          // snapshot after barrier
    for (int i = t; i < n; i += 1024) {
      unsigned u = f2u(s[i]);
      if (round == 0 || (u >> (shift + 8)) == pref)
        atomicAdd(&hist[(u >> shift) & 255], 1);
    }
    __syncthreads();
    if (t < 256) suf[t] = hist[255 - t];
    __syncthreads();
    for (int off = 1; off < 256; off <<= 1) {
      int v = (t < 256 && t >= off) ? suf[t - off] : 0;
      __syncthreads();
      if (t < 256) suf[t] += v;
      __syncthreads();
    }
    if (t < 256) {
      int prev = (t == 0) ? 0 : suf[t - 1];
      if (suf[t] >= krem && prev < krem) {
        sh_prefix = (pref << 8) | (unsigned)(255 - t);
        sh_krem = krem - prev;
      }
    }
    __syncthreads();
  }
  if (t == 0) {
    unsigned u = sh_prefix;
    out[0] = (u & 0x80000000u) ? __uint_as_float(u & 0x7fffffffu)
                               : __uint_as_float(~u);
  }
}

// deterministic compaction (+ inverse perm): s>thr asc idx, ties asc idx.
__global__ void compact_kernel(const float* __restrict__ s, const float* __restrict__ thrp,
                               int n, int k, int* __restrict__ perm,
                               float* __restrict__ vals, int* __restrict__ inv) {
  __shared__ int cg[1024], ce[1024];
  int tid = threadIdx.x;
  float thr = *thrp;
  for (int i = tid; i < n; i += 1024) inv[i] = -1;
  int chunk = n >> 10;
  int beg = tid * chunk;
  int g = 0, e = 0;
  for (int i = 0; i < chunk; ++i) {
    float v = s[beg + i];
    g += (v > thr); e += (v == thr);
  }
  cg[tid] = g; ce[tid] = e; __syncthreads();
  for (int off = 1; off < 1024; off <<= 1) {
    int a = (tid >= off) ? cg[tid - off] : 0;
    int b = (tid >= off) ? ce[tid - off] : 0;
    __syncthreads();
    cg[tid] += a; ce[tid] += b;
    __syncthreads();
  }
  int total_gt = cg[1023];
  int pg = cg[tid] - g;
  int pe = ce[tid] - e;
  int need = k - total_gt;
  for (int i = 0; i < chunk; ++i) {
    float v = s[beg + i];
    if (v > thr) {
      if (pg < k) { perm[pg] = beg + i; vals[pg] = v; inv[beg + i] = pg; }
      ++pg;
    } else if (v == thr) {
      if (pe < need && total_gt + pe < k) {
        perm[total_gt + pe] = beg + i; vals[total_gt + pe] = v;
        inv[beg + i] = total_gt + pe;
      }
      ++pe;
    }
  }
}

__global__ void gather_bf(const bf16* __restrict__ src, int lda,
                          const int* __restrict__ perm, bf16* __restrict__ R, int n) {
  int j = blockIdx.x, t = threadIdx.x;
  int r = perm[j];
  const bf16* s = src + (size_t)r * lda;
  bf16* o = R + (size_t)j * n;
  for (int c4 = t * 4; c4 < n; c4 += 1024) {
    bf16x4 v = *(const bf16x4*)&s[c4];
    if (r >= c4 && r < c4 + 4) v[r - c4] = (bf16)1.0f;
    *(bf16x4*)&o[c4] = v;
  }
}

__global__ void gather_f32(const float* __restrict__ src, int lda,
                           const int* __restrict__ perm, bf16* __restrict__ R, int n) {
  int j = blockIdx.x, t = threadIdx.x;
  int r = perm[j];
  const float* s = src + (size_t)r * lda;
  bf16* o = R + (size_t)j * n;
  for (int c4 = t * 4; c4 < n; c4 += 1024) {
    floatx4 v = *(const floatx4*)(s + c4);
    bf16x4 ob;
#pragma unroll
    for (int e = 0; e < 4; ++e)
      ob[e] = (c4 + e == r) ? (bf16)1.0f : (bf16)v[e];
    *(bf16x4*)&o[c4] = ob;
  }
}

// y = dn[r]*(Agg + 2*Z) + bias; relu?; write Agg in-place; BN col stats.
__global__ void gcn_post(float* __restrict__ acc, const float* __restrict__ Zf,
                         const float* __restrict__ dn, const float* __restrict__ bias,
                         float* __restrict__ stats, int relu) {
  int c = threadIdx.x;
  int r0 = blockIdx.x * 16;
  float b = bias[c];
  float s = 0.f, qq = 0.f;
  for (int i = 0; i < 16; ++i) {
    int r = r0 + i;
    float v = dn[r] * (acc[(size_t)r * 128 + c] + 2.0f * Zf[(size_t)r * 128 + c]) + b;
    if (relu) v = fmaxf(v, 0.f);
    acc[(size_t)r * 128 + c] = v;
    s += v; qq += v * v;
  }
  atomicAdd(&stats[c], s);
  atomicAdd(&stats[128 + c], qq);
}

// BN apply (coef recomputed per block) + optional fused pooling score.
__global__ void bn_apply(const float* __restrict__ H, const float* __restrict__ stats,
                         const float* __restrict__ g, const float* __restrict__ b,
                         int n, float* __restrict__ xout,
                         const float* __restrict__ pw, const float* __restrict__ invp,
                         float* __restrict__ scores) {
  int r = blockIdx.x, c = threadIdx.x;
  float m = stats[c] / n;
  float var = stats[128 + c] / n - m * m;
  float sc = g[c] / sqrtf(var + 1e-5f);
  float off = b[c] - m * sc;
  float v = sc * H[(size_t)r * 128 + c] + off;
  xout[(size_t)r * 128 + c] = v;
  if (pw) {
    __shared__ float red[128];
    red[c] = v * pw[c]; __syncthreads();
    for (int o = 64; o; o >>= 1) {
      if (c < o) red[c] += red[c + o];
      __syncthreads();
    }
    if (c == 0) scores[r] = tanhf(red[0] * invp[0]);
  }
}

// ---------------------------------------------------------------------------
extern "C" void kernel_launch(void* const* d_in, const int* in_sizes, int n_in,
                              void* d_out, int out_size, void* d_ws, size_t ws_size,
                              hipStream_t stream) {
  const float* x_in   = (const float*)d_in[0];
  const float* adj    = (const float*)d_in[1];
  const float* conv_w = (const float*)d_in[2];
  const float* conv_b = (const float*)d_in[3];
  const float* pool_w = (const float*)d_in[4];
  const float* bn_g   = (const float*)d_in[5];
  const float* bn_b   = (const float*)d_in[6];
  float* out = (float*)d_out;
  (void)in_sizes; (void)n_in; (void)out_size; (void)ws_size;

  char* p = (char*)d_ws;
  auto alloc = [&](size_t bytes) -> void* {
    void* r = (void*)p;
    p += (bytes + 255) & ~(size_t)255;
    return r;
  };
  bf16*  Ah0bf = (bf16*)alloc(4096ull * 4096 * 2);
  bf16*  A1bf  = (bf16*)alloc(2048ull * 2048 * 2);
  float* A2f   = (float*)alloc(1024ull * 1024 * 4);
  float* A3f   = (float*)alloc(512ull * 512 * 4);
  bf16*  Rbuf  = (bf16*)alloc(2048ull * 4096 * 2);
  float* Cs    = (float*)alloc(136ull * 4 * 16384 * 4);
  float* Z     = (float*)alloc(4096ull * 128 * 4);
  bf16*  Zht   = (bf16*)alloc(128ull * 4096 * 2);
  bf16*  Zmt   = (bf16*)alloc(128ull * 4096 * 2);
  bf16*  Zlt   = (bf16*)alloc(128ull * 4096 * 2);
  float* Agg   = (float*)alloc(4096ull * 128 * 4);
  float* res0  = (float*)alloc(4096ull * 128 * 4);
  float* res1  = (float*)alloc(2048ull * 128 * 4);
  float* res2  = (float*)alloc(1024ull * 128 * 4);
  float* xb0   = (float*)alloc(512ull * 128 * 4);
  float* xb1   = (float*)alloc(1024ull * 128 * 4);
  float* xb2   = (float*)alloc(2048ull * 128 * 4);
  bf16*  Wh    = (bf16*)alloc(7ull * 16384 * 2);
  bf16*  Wm    = (bf16*)alloc(7ull * 16384 * 2);
  bf16*  Wl    = (bf16*)alloc(7ull * 16384 * 2);
  float* scores = (float*)alloc(4096 * 4);
  float* thrb  = (float*)alloc(256);
  int*   perm0 = (int*)alloc(2048 * 4);
  int*   perm1 = (int*)alloc(1024 * 4);
  int*   perm2 = (int*)alloc(512 * 4);
  int*   inv0  = (int*)alloc(4096 * 4);
  int*   inv1  = (int*)alloc(2048 * 4);
  int*   inv2  = (int*)alloc(1024 * 4);
  float* vals0 = (float*)alloc(2048 * 4);
  float* vals1 = (float*)alloc(1024 * 4);
  float* vals2 = (float*)alloc(512 * 4);
  float* dn0   = (float*)alloc(4096 * 4);
  float* dn1   = (float*)alloc(2048 * 4);
  float* dn2   = (float*)alloc(1024 * 4);
  float* dn3   = (float*)alloc(512 * 4);
  float* invp  = (float*)alloc(256);
  float* stats = (float*)alloc(1024);

  // GCN layer; (perm,vals) fuses pooling gather, (up,inv) fuses unpool add;
  // (pw,ip) fuses the next pool's score into bn_apply.
  auto gcn = [&](int nr, const bf16* Abf, const float* Af32, const float* dnv,
                 int layer, const float* xsrc, const int* perm, const float* vals,
                 const float* up, const int* inv, float* xout, int relu, int aTwo,
                 const float* pw, const float* ip) {
    xw_split<<<nr / 128, 256, 0, stream>>>(
        xsrc, perm, vals, up, inv,
        Wh + layer * 16384, Wm + layer * 16384, Wl + layer * 16384, dnv,
        Z, Zht, Zmt, Zlt, nr, Agg, stats);
    if (Abf)
      agg_bf<<<dim3(nr / 128, 8), 256, 0, stream>>>(
          Abf, nr, Zht, Zmt, Zlt, nr, Agg, nr / 256);
    else
      agg_split<<<dim3(nr / 128, 8), 256, 0, stream>>>(
          Af32, nr, Zht, Zmt, Zlt, nr, Agg, nr / 256, aTwo);
    gcn_post<<<nr / 16, 128, 0, stream>>>(Agg, Z, dnv, conv_b + layer * 128, stats, relu);
    bn_apply<<<nr, 128, 0, stream>>>(Agg, stats, bn_g + layer * 128, bn_b + layer * 128,
                                     nr, xout, pw, ip, scores);
  };

  // Pool (round-5 machinery): top-k -> gather R=(A+I)[perm] -> R R^T -> A_new.
  auto pool = [&](int n, const bf16* srcBf, const float* srcF32,
                  bf16* outBf, float* outF32, float* dnNew,
                  int* perm, float* vals, int* inv, int splitZ) {
    int k = n / 2, G = k / 128, pairs = G * (G + 1) / 2;
    kth_radix<<<1, 1024, 0, stream>>>(scores, n, k, thrb);
    compact_kernel<<<1, 1024, 0, stream>>>(scores, thrb, n, k, perm, vals, inv);
    if (srcBf) gather_bf<<<k, 256, 0, stream>>>(srcBf, n, perm, Rbuf, n);
    else       gather_f32<<<k, 256, 0, stream>>>(srcF32, n, perm, Rbuf, n);
    gemm_sym<<<dim3(pairs, splitZ), 256, 0, stream>>>(Rbuf, Cs, n, n / (splitZ * 32), G);
    sym_post<<<pairs, 128, 0, stream>>>(Cs, outBf, outF32, k, G, pairs, splitZ);
    if (outBf) dn_rows_bf<<<k, 256, 0, stream>>>(outBf, k, dnNew, k);
    else       dn_rows<<<k, 256, 0, stream>>>(outF32, k, dnNew, k);
  };

  // ---- prep ----
  pnorm_kernel<<<1, 128, 0, stream>>>(pool_w, invp);
  split_w<<<448, 256, 0, stream>>>(conv_w, Wh, Wm, Wl);
  adj2bf<<<4096, 256, 0, stream>>>(adj, Ah0bf, dn0, 4096);

  // ---- down ----
  gcn(4096, Ah0bf, nullptr, dn0, 0, x_in, nullptr, nullptr, nullptr, nullptr,
      res0, 1, 0, pool_w + 0, invp + 0);
  pool(4096, Ah0bf, nullptr, A1bf, nullptr, dn1, perm0, vals0, inv0, 4);
  gcn(2048, A1bf, nullptr, dn1, 1, res0, perm0, vals0, nullptr, nullptr,
      res1, 1, 0, pool_w + 128, invp + 1);
  pool(2048, A1bf, nullptr, nullptr, A2f, dn2, perm1, vals1, inv1, 4);
  gcn(1024, nullptr, A2f, dn2, 2, res1, perm1, vals1, nullptr, nullptr,
      res2, 1, 1, pool_w + 256, invp + 2);
  pool(1024, nullptr, A2f, nullptr, A3f, dn3, perm2, vals2, inv2, 8);
  gcn(512, nullptr, A3f, dn3, 3, res2, perm2, vals2, nullptr, nullptr,
      xb0, 1, 1, nullptr, nullptr);

  // ---- up ---- (unpool add fused into xw_split; res buffers stay intact)
  gcn(1024, nullptr, A2f, dn2, 4, res2, nullptr, nullptr, xb0, inv2,
      xb1, 1, 1, nullptr, nullptr);
  gcn(2048, A1bf, nullptr, dn1, 5, res1, nullptr, nullptr, xb1, inv1,
      xb2, 1, 0, nullptr, nullptr);
  gcn(4096, Ah0bf, nullptr, dn0, 6, res0, nullptr, nullptr, xb2, inv0,
      out, 0, 0, nullptr, nullptr);
}